// Round 12
// baseline (410.816 us; speedup 1.0000x reference)
//
#include <hip/hip_runtime.h>
#include <math.h>

#define D_MODEL 512
#define SEQ     1024
#define BATCH   4
#define N_LAYERS 2
#define N_HEAD  8
#define D_HEAD  64
#define D_INNER 1024
#define NTOK    (BATCH*SEQ)   // 4096
#define LN_EPS  1e-3f

typedef float f32x4 __attribute__((ext_vector_type(4)));
typedef short bf16x8 __attribute__((ext_vector_type(8)));
typedef unsigned short ushort_t;
typedef unsigned int uint_t;
typedef unsigned long long ull_t;

// fp32 -> bf16 round-to-nearest-even
__device__ inline ushort_t f2bf(float f) {
    uint_t u = __float_as_uint(f);
    u += 0x7FFFu + ((u >> 16) & 1u);
    return (ushort_t)(u >> 16);
}
__device__ inline float bf2f(ushort_t h) {
    return __uint_as_float((uint_t)h << 16);
}

// ---------------------------------------------------------------- add pos enc
// X = x + pe (fp32 residual path); Xrawbf = bf16(x) (layer-1 xW GEMM input)
__global__ void add_pos_kernel(const float* __restrict__ x,
                               const float* __restrict__ pe,
                               float* __restrict__ X,
                               ushort_t* __restrict__ Xrawbf) {
    int idx = blockIdx.x * blockDim.x + threadIdx.x;   // over NTOK*D_MODEL
    int l = (idx / D_MODEL) % SEQ;
    int d = idx % D_MODEL;
    float xv = x[idx];
    X[idx] = xv + pe[l * D_MODEL + d];
    Xrawbf[idx] = f2bf(xv);
}

// ---------------------------------------------------------------- weight conv
__global__ void conv_bf16_kernel(const float* __restrict__ src,
                                 ushort_t* __restrict__ dst, int n) {
    int idx = blockIdx.x * 256 + threadIdx.x;
    if (idx < n) dst[idx] = f2bf(src[idx]);
}

// Pack per-layer QKV weights into Bt layout [1536][512] (hi, optional lo):
// row n: which=n>>9, h=(n>>6)&7, d=n&63 ; Bt[n][k] = W_which[h][k][d]
__global__ void conv_qkvw_kernel(const float* __restrict__ wq,
                                 const float* __restrict__ wk,
                                 const float* __restrict__ wv,
                                 ushort_t* __restrict__ hi,
                                 ushort_t* __restrict__ lo) {
    int idx = blockIdx.x * 256 + threadIdx.x;   // over 1536*512
    int n = idx >> 9, k = idx & 511;
    int which = n >> 9, h = (n >> 6) & 7, d = n & 63;
    const float* W = (which == 0) ? wq : (which == 1) ? wk : wv;
    float v = W[((size_t)h * D_MODEL + k) * D_HEAD + d];
    ushort_t hv = f2bf(v);
    hi[idx] = hv;
    if (lo) lo[idx] = f2bf(v - bf2f(hv));
}

// ---------------------------------------------------------------- QKV scatter
// n in [0,1536): which=n>>9 (0:Q 1:K 2:V), head=(n>>6)&7, d=n&63.
// Optional pew add (layer 1): acc += peW[l][n], broadcast over batch.
// Q,K -> hi/lo bf16 [hb][seq][64]; V -> bf16 transposed [hb][dim][seq].
__device__ inline void qkv_scatter(f32x4 a, int n, int m_base,
                                   const float* __restrict__ pew,
                                   ushort_t* Qhi, ushort_t* Qlo,
                                   ushort_t* Khi, ushort_t* Klo,
                                   ushort_t* Vt) {
    int which = n >> 9, hd = n & 511;
    int head = hd >> 6, d = hd & 63;
    int hb = head * BATCH + (m_base >> 10);
    int l  = m_base & 1023;
    if (pew) {
#pragma unroll
        for (int r = 0; r < 4; r++) a[r] += pew[(size_t)(l + r) * 1536 + n];
    }
    if (which == 2) {
        ushort4 pk = make_ushort4(f2bf(a[0]), f2bf(a[1]), f2bf(a[2]), f2bf(a[3]));
        *(ushort4*)(Vt + ((size_t)hb * D_HEAD + d) * SEQ + l) = pk;
    } else {
        ushort_t* H = (which == 0) ? Qhi : Khi;
        ushort_t* L = (which == 0) ? Qlo : Klo;
#pragma unroll
        for (int r = 0; r < 4; r++) {
            float v = a[r];
            ushort_t hv = f2bf(v);
            size_t off = ((size_t)hb * SEQ + l + r) * D_HEAD + d;
            H[off] = hv;
            L[off] = f2bf(v - bf2f(hv));
        }
    }
}

// ---------------------------------------------------------------- MFMA GEMM
// C[M,N] = A[M,K] @ Bt[N,K]^T ; A,Bt bf16 row-major, acc fp32.
// Block: 256 thr = 4 waves (2x2), tile TM x TN (proven config: 64x64 —
// 128-tiles regressed at these shapes: grid too small to hide barriers, R10).
// MODE 0: (+pew) qkv_scatter  MODE 1: +bias, relu, bf16 out  MODE 2: +bias, fp32 out
template<int MODE, int TM, int TN>
__global__ __launch_bounds__(256, 2)
void gemm_kernel(const ushort_t* __restrict__ A, const ushort_t* __restrict__ Bt,
                 const float* __restrict__ bias, const float* __restrict__ pew,
                 float* __restrict__ outF, ushort_t* __restrict__ outB,
                 ushort_t* __restrict__ Qhi, ushort_t* __restrict__ Qlo,
                 ushort_t* __restrict__ Khi, ushort_t* __restrict__ Klo,
                 ushort_t* __restrict__ Vt,
                 int M, int N, int K) {
    constexpr int WM = TM / 2, WN = TN / 2;
    constexpr int MT = WM / 16, NT = WN / 16;
    __shared__ ushort_t As[TM][72];   // +8 pad: keeps 16B align, breaks bank alias
    __shared__ ushort_t Bs[TN][72];
    const int tid = threadIdx.x;
    const int m0 = blockIdx.y * TM, n0 = blockIdx.x * TN;
    const int w = tid >> 6, lane = tid & 63;
    const int wr = w >> 1, wc = w & 1;
    const int col = lane & 15, quad = lane >> 4;

    f32x4 acc[MT][NT] = {};

    for (int k0 = 0; k0 < K; k0 += 64) {
        __syncthreads();
#pragma unroll
        for (int p = 0; p < TM / 32; p++) {    // TM*8 chunk tasks
            int idx = p * 256 + tid;
            int row = idx >> 3, ch = (idx & 7) * 8;
            *(uint4*)(&As[row][ch]) =
                *(const uint4*)(A + (size_t)(m0 + row) * K + k0 + ch);
        }
#pragma unroll
        for (int p = 0; p < TN / 32; p++) {
            int idx = p * 256 + tid;
            int row = idx >> 3, ch = (idx & 7) * 8;
            *(uint4*)(&Bs[row][ch]) =
                *(const uint4*)(Bt + (size_t)(n0 + row) * K + k0 + ch);
        }
        __syncthreads();
#pragma unroll
        for (int ks = 0; ks < 64; ks += 32) {
            bf16x8 af[MT], bfr[NT];
#pragma unroll
            for (int t = 0; t < MT; t++)
                af[t] = *(const bf16x8*)(&As[wr * WM + t * 16 + col][ks + quad * 8]);
#pragma unroll
            for (int t = 0; t < NT; t++)
                bfr[t] = *(const bf16x8*)(&Bs[wc * WN + t * 16 + col][ks + quad * 8]);
#pragma unroll
            for (int mt = 0; mt < MT; mt++)
#pragma unroll
                for (int nt = 0; nt < NT; nt++)
                    acc[mt][nt] = __builtin_amdgcn_mfma_f32_16x16x32_bf16(
                        af[mt], bfr[nt], acc[mt][nt], 0, 0, 0);
        }
    }

#pragma unroll
    for (int mt = 0; mt < MT; mt++) {
#pragma unroll
        for (int nt = 0; nt < NT; nt++) {
            int n = n0 + wc * WN + nt * 16 + col;
            int m_base = m0 + wr * WM + mt * 16 + quad * 4;
            if (MODE == 0) {
                qkv_scatter(acc[mt][nt], n, m_base, pew, Qhi, Qlo, Khi, Klo, Vt);
            } else {
#pragma unroll
                for (int r = 0; r < 4; r++) {
                    int m = m_base + r;
                    float v = acc[mt][nt][r];
                    if (MODE == 1) {
                        float t = fmaxf(v + bias[n], 0.f);
                        outB[(size_t)m * N + n] = f2bf(t);
                    } else {
                        outF[(size_t)m * N + n] = v + bias[n];
                    }
                }
            }
        }
    }
}

// ---------------------------------------------------------------- hi/lo GEMM
// High-precision bf16 GEMM: A fp32 split in-kernel into hi+lo bf16; Bt
// pre-split (hi,lo). acc = Ah*Bh + Ah*Bl + Al*Bh (~1e-5 rel). fp32 out [M][N].
// Used for peW = pos_enc @ Wqkv (M=SEQ=1024).
__global__ __launch_bounds__(256, 2)
void gemm_hilo_kernel(const float* __restrict__ A,
                      const ushort_t* __restrict__ Bh,
                      const ushort_t* __restrict__ Bl,
                      float* __restrict__ outF, int M, int N, int K) {
    __shared__ ushort_t Ash[64][72];
    __shared__ ushort_t Asl[64][72];
    __shared__ ushort_t Bsh[64][72];
    __shared__ ushort_t Bsl[64][72];
    const int tid = threadIdx.x;
    const int m0 = blockIdx.y * 64, n0 = blockIdx.x * 64;
    const int w = tid >> 6, lane = tid & 63;
    const int wm = (w >> 1) * 32, wn = (w & 1) * 32;
    const int col = lane & 15, quad = lane >> 4;

    f32x4 acc[2][2] = {};

    for (int k0 = 0; k0 < K; k0 += 64) {
        __syncthreads();
#pragma unroll
        for (int p = 0; p < 4; p++) {
            int idx = p * 256 + tid;
            int row = idx >> 4, c4 = (idx & 15) * 4;
            float4 v = *(const float4*)(A + (size_t)(m0 + row) * K + k0 + c4);
            ushort_t h0 = f2bf(v.x), h1 = f2bf(v.y), h2 = f2bf(v.z), h3 = f2bf(v.w);
            *(ushort4*)(&Ash[row][c4]) = make_ushort4(h0, h1, h2, h3);
            *(ushort4*)(&Asl[row][c4]) = make_ushort4(
                f2bf(v.x - bf2f(h0)), f2bf(v.y - bf2f(h1)),
                f2bf(v.z - bf2f(h2)), f2bf(v.w - bf2f(h3)));
        }
#pragma unroll
        for (int p = 0; p < 2; p++) {
            int idx = p * 256 + tid;
            int row = idx >> 3, ch = (idx & 7) * 8;
            *(uint4*)(&Bsh[row][ch]) =
                *(const uint4*)(Bh + (size_t)(n0 + row) * K + k0 + ch);
            *(uint4*)(&Bsl[row][ch]) =
                *(const uint4*)(Bl + (size_t)(n0 + row) * K + k0 + ch);
        }
        __syncthreads();
#pragma unroll
        for (int ks = 0; ks < 64; ks += 32) {
            bf16x8 ah[2], al[2], bh[2], bl[2];
#pragma unroll
            for (int t = 0; t < 2; t++) {
                ah[t] = *(const bf16x8*)(&Ash[wm + t * 16 + col][ks + quad * 8]);
                al[t] = *(const bf16x8*)(&Asl[wm + t * 16 + col][ks + quad * 8]);
                bh[t] = *(const bf16x8*)(&Bsh[wn + t * 16 + col][ks + quad * 8]);
                bl[t] = *(const bf16x8*)(&Bsl[wn + t * 16 + col][ks + quad * 8]);
            }
#pragma unroll
            for (int mt = 0; mt < 2; mt++)
#pragma unroll
                for (int nt = 0; nt < 2; nt++) {
                    acc[mt][nt] = __builtin_amdgcn_mfma_f32_16x16x32_bf16(
                        ah[mt], bh[nt], acc[mt][nt], 0, 0, 0);
                    acc[mt][nt] = __builtin_amdgcn_mfma_f32_16x16x32_bf16(
                        ah[mt], bl[nt], acc[mt][nt], 0, 0, 0);
                    acc[mt][nt] = __builtin_amdgcn_mfma_f32_16x16x32_bf16(
                        al[mt], bh[nt], acc[mt][nt], 0, 0, 0);
                }
        }
    }

#pragma unroll
    for (int mt = 0; mt < 2; mt++)
#pragma unroll
        for (int nt = 0; nt < 2; nt++) {
            int n = n0 + wn + nt * 16 + col;
#pragma unroll
            for (int r = 0; r < 4; r++) {
                int m = m0 + wm + mt * 16 + quad * 4 + r;
                outF[(size_t)m * N + n] = acc[mt][nt][r];
            }
        }
}

// ---------------------------------------------------------------- attention
// MFMA flash attention, register-prefetch + LDS double-buffer (1 barrier/tile)
// + __threadfence_block() between P write and P read (fixes the TBAA UB that
// broke R8's dbuf attempt). Block = 64 Q-rows of one (b,h).
// XCD swizzle: all 16 Q-tiles of one hb land on one XCD (K/V L2-resident).
__global__ __launch_bounds__(256, 2)
void attention_kernel(const ushort_t* __restrict__ Qhi,
                      const ushort_t* __restrict__ Qlo,
                      const ushort_t* __restrict__ Khi,
                      const ushort_t* __restrict__ Klo,
                      const ushort_t* __restrict__ Vt,
                      float* __restrict__ O) {
    const int bid = blockIdx.x;          // 512
    const int j   = bid >> 3;
    const int hb  = (bid & 7) * 4 + (j >> 4);
    const int qt  = j & 15;
    const int h = hb >> 2, b = hb & 3;
    const int tid = threadIdx.x;
    const int w = tid >> 6, lane = tid & 63;
    const int col = lane & 15, quad = lane >> 4;
    const size_t kbase = (size_t)hb * SEQ * D_HEAD;
    const size_t vbase = (size_t)hb * D_HEAD * SEQ;

    __shared__ ushort_t Kh[2][64][72];   // 18 KB
    __shared__ ushort_t Kl[2][64][72];
    __shared__ ushort_t Vs[2][64][72];   // V^T tile [dim][key]
    __shared__ ushort_t Pl[4][16][68];   // per-wave P [qrow][key]  (8.5 KB)

    const int srow = tid >> 3, sch = (tid & 7) * 8;   // staging task

    // Q fragments hi/lo (A-layout) straight from global
    bf16x8 qh[2], ql[2];
    {
        const ushort_t* qp = Qhi + kbase + (size_t)(qt * 64 + w * 16 + col) * D_HEAD;
        const ushort_t* lp = Qlo + kbase + (size_t)(qt * 64 + w * 16 + col) * D_HEAD;
        qh[0] = *(const bf16x8*)(qp + quad * 8);
        qh[1] = *(const bf16x8*)(qp + 32 + quad * 8);
        ql[0] = *(const bf16x8*)(lp + quad * 8);
        ql[1] = *(const bf16x8*)(lp + 32 + quad * 8);
    }

    f32x4 acco[4] = {};
    float mrun[4], lrun[4];
#pragma unroll
    for (int r = 0; r < 4; r++) { mrun[r] = -1e30f; lrun[r] = 0.f; }
    const float inv_temper = 0.04419417382415922f;  // 1/sqrt(512)

    // stage tile 0 into buf 0
    uint4 rk[2], rl[2], rv[2];
#pragma unroll
    for (int p = 0; p < 2; p++) {
        int row = srow + p * 32;
        rk[p] = *(const uint4*)(Khi + kbase + (size_t)row * D_HEAD + sch);
        rl[p] = *(const uint4*)(Klo + kbase + (size_t)row * D_HEAD + sch);
        rv[p] = *(const uint4*)(Vt + vbase + (size_t)row * SEQ + sch);
    }
#pragma unroll
    for (int p = 0; p < 2; p++) {
        int row = srow + p * 32;
        *(uint4*)(&Kh[0][row][sch]) = rk[p];
        *(uint4*)(&Kl[0][row][sch]) = rl[p];
        *(uint4*)(&Vs[0][row][sch]) = rv[p];
    }

    int cur = 0;
    for (int t0 = 0; t0 < SEQ; t0 += 64) {
        __syncthreads();   // buf[cur] staged by all; buf[cur^1] reads done
        const int nt0 = t0 + 64;
        if (nt0 < SEQ) {
#pragma unroll
            for (int p = 0; p < 2; p++) {
                int row = srow + p * 32;
                rk[p] = *(const uint4*)(Khi + kbase + (size_t)(nt0 + row) * D_HEAD + sch);
                rl[p] = *(const uint4*)(Klo + kbase + (size_t)(nt0 + row) * D_HEAD + sch);
                rv[p] = *(const uint4*)(Vt + vbase + (size_t)row * SEQ + nt0 + sch);
            }
        }

        // S = Q K^T (hi/lo), keys nt*16+col, rows quad*4+r
        float sc[4][4];
#pragma unroll
        for (int nt = 0; nt < 4; nt++) {
            bf16x8 bh0 = *(const bf16x8*)(&Kh[cur][nt * 16 + col][quad * 8]);
            bf16x8 bh1 = *(const bf16x8*)(&Kh[cur][nt * 16 + col][32 + quad * 8]);
            bf16x8 bl0 = *(const bf16x8*)(&Kl[cur][nt * 16 + col][quad * 8]);
            bf16x8 bl1 = *(const bf16x8*)(&Kl[cur][nt * 16 + col][32 + quad * 8]);
            f32x4 s = {};
            s = __builtin_amdgcn_mfma_f32_16x16x32_bf16(qh[0], bh0, s, 0, 0, 0);
            s = __builtin_amdgcn_mfma_f32_16x16x32_bf16(qh[1], bh1, s, 0, 0, 0);
            s = __builtin_amdgcn_mfma_f32_16x16x32_bf16(qh[0], bl0, s, 0, 0, 0);
            s = __builtin_amdgcn_mfma_f32_16x16x32_bf16(qh[1], bl1, s, 0, 0, 0);
            s = __builtin_amdgcn_mfma_f32_16x16x32_bf16(ql[0], bh0, s, 0, 0, 0);
            s = __builtin_amdgcn_mfma_f32_16x16x32_bf16(ql[1], bh1, s, 0, 0, 0);
#pragma unroll
            for (int r = 0; r < 4; r++) sc[nt][r] = s[r] * inv_temper;
        }

        // online softmax: row stats via quad shfl_xor reductions
        float tmax[4];
#pragma unroll
        for (int r = 0; r < 4; r++)
            tmax[r] = fmaxf(fmaxf(sc[0][r], sc[1][r]), fmaxf(sc[2][r], sc[3][r]));
#pragma unroll
        for (int mask = 1; mask < 16; mask <<= 1)
#pragma unroll
            for (int r = 0; r < 4; r++)
                tmax[r] = fmaxf(tmax[r], __shfl_xor(tmax[r], mask, 64));

        float alpha[4], tsum[4];
#pragma unroll
        for (int r = 0; r < 4; r++) {
            float mn = fmaxf(mrun[r], tmax[r]);
            alpha[r] = __expf(mrun[r] - mn);
            mrun[r] = mn;
            tsum[r] = 0.f;
        }
#pragma unroll
        for (int nt = 0; nt < 4; nt++)
#pragma unroll
            for (int r = 0; r < 4; r++) {
                float pv = __expf(sc[nt][r] - mrun[r]);
                tsum[r] += pv;
                Pl[w][quad * 4 + r][nt * 16 + col] = f2bf(pv);
            }
#pragma unroll
        for (int mask = 1; mask < 16; mask <<= 1)
#pragma unroll
            for (int r = 0; r < 4; r++)
                tsum[r] += __shfl_xor(tsum[r], mask, 64);
#pragma unroll
        for (int r = 0; r < 4; r++)
            lrun[r] = lrun[r] * alpha[r] + tsum[r];
#pragma unroll
        for (int nt = 0; nt < 4; nt++)
#pragma unroll
            for (int r = 0; r < 4; r++)
                acco[nt][r] *= alpha[r];

        // Order the Pl stores before the type-punned reads below (wave-local
        // visibility; also a compiler fence against TBAA reordering).
        __threadfence_block();

        // P (A-layout) and PV
        union { ulong2 u; bf16x8 v; } a0, a1;
        a0.u.x = *(const ull_t*)(&Pl[w][col][quad * 8]);
        a0.u.y = *(const ull_t*)(&Pl[w][col][quad * 8 + 4]);
        a1.u.x = *(const ull_t*)(&Pl[w][col][32 + quad * 8]);
        a1.u.y = *(const ull_t*)(&Pl[w][col][32 + quad * 8 + 4]);
#pragma unroll
        for (int nt = 0; nt < 4; nt++) {
            bf16x8 bv0 = *(const bf16x8*)(&Vs[cur][nt * 16 + col][quad * 8]);
            bf16x8 bv1 = *(const bf16x8*)(&Vs[cur][nt * 16 + col][32 + quad * 8]);
            acco[nt] = __builtin_amdgcn_mfma_f32_16x16x32_bf16(a0.v, bv0, acco[nt], 0, 0, 0);
            acco[nt] = __builtin_amdgcn_mfma_f32_16x16x32_bf16(a1.v, bv1, acco[nt], 0, 0, 0);
        }

        // store prefetched tile to the other buffer
        if (nt0 < SEQ) {
#pragma unroll
            for (int p = 0; p < 2; p++) {
                int row = srow + p * 32;
                *(uint4*)(&Kh[cur ^ 1][row][sch]) = rk[p];
                *(uint4*)(&Kl[cur ^ 1][row][sch]) = rl[p];
                *(uint4*)(&Vs[cur ^ 1][row][sch]) = rv[p];
            }
        }
        cur ^= 1;
    }

    // epilogue: O[b][row][h*64 + dim], dim = nt*16+col, row = qt*64+w*16+quad*4+r
#pragma unroll
    for (int nt = 0; nt < 4; nt++) {
#pragma unroll
        for (int r = 0; r < 4; r++) {
            int row = qt * 64 + w * 16 + quad * 4 + r;
            O[((size_t)b * SEQ + row) * D_MODEL + h * D_HEAD + nt * 16 + col]
                = acco[nt][r] / lrun[r];
        }
    }
}

// ---------------------------------------------------------------- add + LN
__device__ inline float block_sum_256(float v, float* tmp) {
#pragma unroll
    for (int off = 32; off > 0; off >>= 1) v += __shfl_down(v, off, 64);
    if ((threadIdx.x & 63) == 0) tmp[threadIdx.x >> 6] = v;
    __syncthreads();
    return tmp[0] + tmp[1] + tmp[2] + tmp[3];
}

// Writes fp32 Out AND bf16 OutBf. Safe for Out==R (in-place).
__global__ void add_norm_kernel(const float* __restrict__ A,
                                const float* __restrict__ R,
                                const float* __restrict__ ga,
                                const float* __restrict__ gb,
                                float* __restrict__ Out,
                                ushort_t* __restrict__ OutBf) {
    int tok = blockIdx.x, tid = threadIdx.x;
    __shared__ float t1[4], t2[4];
    size_t base = (size_t)tok * D_MODEL;
    float z0 = A[base + tid]       + R[base + tid];
    float z1 = A[base + tid + 256] + R[base + tid + 256];
    float s = block_sum_256(z0 + z1, t1);
    float mu = s * (1.f / (float)D_MODEL);
    float d0 = z0 - mu, d1 = z1 - mu;
    float ss = block_sum_256(d0 * d0 + d1 * d1, t2);
    float sigma = sqrtf(ss * (1.f / (float)(D_MODEL - 1)));
    float inv = 1.f / (sigma + LN_EPS);
    float r0 = d0 * inv * ga[tid]       + gb[tid];
    float r1 = d1 * inv * ga[tid + 256] + gb[tid + 256];
    Out[base + tid]         = r0;
    Out[base + tid + 256]   = r1;
    OutBf[base + tid]       = f2bf(r0);
    OutBf[base + tid + 256] = f2bf(r1);
}

// ---------------------------------------------------------------- launch
extern "C" void kernel_launch(void* const* d_in, const int* in_sizes, int n_in,
                              void* d_out, int out_size, void* d_ws, size_t ws_size,
                              hipStream_t stream) {
    const float* x     = (const float*)d_in[0];
    const float* pe    = (const float*)d_in[1];
    const float* w_qs  = (const float*)d_in[2];
    const float* w_ks  = (const float*)d_in[3];
    const float* w_vs  = (const float*)d_in[4];
    const float* ln1_a = (const float*)d_in[5];
    const float* ln1_b = (const float*)d_in[6];
    const float* w1    = (const float*)d_in[7];
    const float* b1    = (const float*)d_in[8];
    const float* w2    = (const float*)d_in[9];
    const float* b2    = (const float*)d_in[10];
    const float* ln2_a = (const float*)d_in[11];
    const float* ln2_b = (const float*)d_in[12];
    float* out = (float*)d_out;

    const size_t NXD = (size_t)NTOK * D_MODEL;       // 2M elements
    char* p = (char*)d_ws;
    float*    X    = (float*)p;     p += NXD * 4;                 // 8 MB
    float*    Ob   = (float*)p;     p += NXD * 4;                 // 8 MB
    ushort_t* Xbf  = (ushort_t*)p;  p += NXD * 2;                 // 4 MB
    ushort_t* Xraw = (ushort_t*)p;  p += NXD * 2;                 // 4 MB  bf16(x)
    ushort_t* Qhi  = (ushort_t*)p;  p += NXD * 2;                 // 4 MB
    ushort_t* Qlo  = (ushort_t*)p;  p += NXD * 2;                 // 4 MB
    ushort_t* Khi  = (ushort_t*)p;  p += NXD * 2;                 // 4 MB
    ushort_t* Klo  = (ushort_t*)p;  p += NXD * 2;                 // 4 MB
    ushort_t* Vt   = (ushort_t*)p;  p += NXD * 2;                 // 4 MB
    ushort_t* Wqkv = (ushort_t*)p;  p += (size_t)N_LAYERS * 1536 * 512 * 2;  // 3 MB (hi)
    ushort_t* WqkvL= (ushort_t*)p;  p += (size_t)1536 * 512 * 2;  // 1.5 MB (lo, layer 0)
    ushort_t* W1b  = (ushort_t*)p;  p += (size_t)N_LAYERS * D_INNER * D_MODEL * 2;  // 2 MB
    ushort_t* W2b  = (ushort_t*)p;  /* 2 MB */
    // Aliases (stream-ordered safe):
    //  H (bf16, 8 MB) = Qhi+Qlo: Q dead after attention; H consumed by FFN2
    //  before next layer's QKV GEMM rewrites Q.
    //  PEW (fp32 [1024][1536], 6 MB) = Ob: produced+consumed before attention
    //  writes Ob in layer 1; unused afterwards.
    ushort_t* Hbf  = Qhi;
    float*    PEW  = Ob;

    add_pos_kernel<<<(int)(NXD / 256), 256, 0, stream>>>(x, pe, X, Xraw);

    for (int i = 0; i < N_LAYERS; i++) {
        conv_qkvw_kernel<<<1536 * 512 / 256, 256, 0, stream>>>(
            w_qs + (size_t)i * N_HEAD * D_MODEL * D_HEAD,
            w_ks + (size_t)i * N_HEAD * D_MODEL * D_HEAD,
            w_vs + (size_t)i * N_HEAD * D_MODEL * D_HEAD,
            Wqkv + (size_t)i * 1536 * 512,
            (i == 0) ? WqkvL : (ushort_t*)nullptr);
    }
    conv_bf16_kernel<<<(N_LAYERS * D_INNER * D_MODEL) / 256, 256, 0, stream>>>(
        w1, W1b, N_LAYERS * D_INNER * D_MODEL);
    conv_bf16_kernel<<<(N_LAYERS * D_MODEL * D_INNER) / 256, 256, 0, stream>>>(
        w2, W2b, N_LAYERS * D_MODEL * D_INNER);

    for (int i = 0; i < N_LAYERS; i++) {
        if (i == 0) {
            // peW = pe @ Wqkv, fp32-accurate (hi/lo), M=1024 (batch-invariant)
            gemm_hilo_kernel<<<dim3(1536 / 64, SEQ / 64), 256, 0, stream>>>(
                pe, Wqkv, WqkvL, PEW, SEQ, 1536, D_MODEL);
            // QKV = xW (plain bf16) + peW (epilogue add) -> hi/lo scatter
            gemm_kernel<0, 64, 64><<<dim3(1536 / 64, NTOK / 64), 256, 0, stream>>>(
                Xraw, Wqkv, nullptr, PEW, nullptr, nullptr,
                Qhi, Qlo, Khi, Klo, Vt, NTOK, 1536, D_MODEL);
        } else {
            gemm_kernel<0, 64, 64><<<dim3(1536 / 64, NTOK / 64), 256, 0, stream>>>(
                Xbf, Wqkv + (size_t)i * 1536 * 512, nullptr, nullptr, nullptr,
                nullptr, Qhi, Qlo, Khi, Klo, Vt, NTOK, 1536, D_MODEL);
        }

        attention_kernel<<<512, 256, 0, stream>>>(Qhi, Qlo, Khi, Klo, Vt, Ob);

        add_norm_kernel<<<NTOK, 256, 0, stream>>>(
            Ob, X, ln1_a + i * D_MODEL, ln1_b + i * D_MODEL, X, Xbf);

        // FFN1: M=4096, N=1024, K=512, bias+relu -> bf16 H (aliases Qhi/Qlo)
        gemm_kernel<1, 64, 64><<<dim3(D_INNER / 64, NTOK / 64), 256, 0, stream>>>(
            Xbf, W1b + (size_t)i * D_INNER * D_MODEL, b1 + (size_t)i * D_INNER,
            nullptr, nullptr, Hbf, nullptr, nullptr, nullptr, nullptr, nullptr,
            NTOK, D_INNER, D_MODEL);

        // FFN2: M=4096, N=512, K=1024, bias -> fp32 Ob
        gemm_kernel<2, 64, 64><<<dim3(D_MODEL / 64, NTOK / 64), 256, 0, stream>>>(
            Hbf, W2b + (size_t)i * D_MODEL * D_INNER, b2 + (size_t)i * D_MODEL,
            nullptr, Ob, nullptr, nullptr, nullptr, nullptr, nullptr, nullptr,
            NTOK, D_MODEL, D_INNER);

        float* dst = (i == N_LAYERS - 1) ? out : X;
        add_norm_kernel<<<NTOK, 256, 0, stream>>>(
            Ob, X, ln2_a + i * D_MODEL, ln2_b + i * D_MODEL, dst, Xbf);
    }
}

// Round 13
// 386.649 us; speedup vs baseline: 1.0625x; 1.0625x over previous
//
#include <hip/hip_runtime.h>
#include <math.h>

#define D_MODEL 512
#define SEQ     1024
#define BATCH   4
#define N_LAYERS 2
#define N_HEAD  8
#define D_HEAD  64
#define D_INNER 1024
#define NTOK    (BATCH*SEQ)   // 4096
#define LN_EPS  1e-3f

typedef float f32x4 __attribute__((ext_vector_type(4)));
typedef short bf16x8 __attribute__((ext_vector_type(8)));
typedef unsigned short ushort_t;
typedef unsigned int uint_t;
typedef unsigned long long ull_t;

// fp32 -> bf16 round-to-nearest-even
__device__ inline ushort_t f2bf(float f) {
    uint_t u = __float_as_uint(f);
    u += 0x7FFFu + ((u >> 16) & 1u);
    return (ushort_t)(u >> 16);
}
__device__ inline float bf2f(ushort_t h) {
    return __uint_as_float((uint_t)h << 16);
}

// ---------------------------------------------------------------- add pos enc
// X = x + pe (fp32 residual path); Xrawbf = bf16(x) (layer-1 xW GEMM input)
__global__ void add_pos_kernel(const float* __restrict__ x,
                               const float* __restrict__ pe,
                               float* __restrict__ X,
                               ushort_t* __restrict__ Xrawbf) {
    int idx = blockIdx.x * blockDim.x + threadIdx.x;   // over NTOK*D_MODEL
    int l = (idx / D_MODEL) % SEQ;
    int d = idx % D_MODEL;
    float xv = x[idx];
    X[idx] = xv + pe[l * D_MODEL + d];
    Xrawbf[idx] = f2bf(xv);
}

// ---------------------------------------------------------------- weight conv
__global__ void conv_bf16_kernel(const float* __restrict__ src,
                                 ushort_t* __restrict__ dst, int n) {
    int idx = blockIdx.x * 256 + threadIdx.x;
    if (idx < n) dst[idx] = f2bf(src[idx]);
}

// Pack per-layer QKV weights into Bt layout [1536][512] (hi, optional lo):
// row n: which=n>>9, h=(n>>6)&7, d=n&63 ; Bt[n][k] = W_which[h][k][d]
__global__ void conv_qkvw_kernel(const float* __restrict__ wq,
                                 const float* __restrict__ wk,
                                 const float* __restrict__ wv,
                                 ushort_t* __restrict__ hi,
                                 ushort_t* __restrict__ lo) {
    int idx = blockIdx.x * 256 + threadIdx.x;   // over 1536*512
    int n = idx >> 9, k = idx & 511;
    int which = n >> 9, h = (n >> 6) & 7, d = n & 63;
    const float* W = (which == 0) ? wq : (which == 1) ? wk : wv;
    float v = W[((size_t)h * D_MODEL + k) * D_HEAD + d];
    ushort_t hv = f2bf(v);
    hi[idx] = hv;
    if (lo) lo[idx] = f2bf(v - bf2f(hv));
}

// ---------------------------------------------------------------- QKV scatter
// n in [0,1536): which=n>>9 (0:Q 1:K 2:V), head=(n>>6)&7, d=n&63.
// Optional pew add (layer 1): acc += peW[l][n], broadcast over batch.
// Q,K -> hi/lo bf16 [hb][seq][64]; V -> bf16 transposed [hb][dim][seq].
__device__ inline void qkv_scatter(f32x4 a, int n, int m_base,
                                   const float* __restrict__ pew,
                                   ushort_t* Qhi, ushort_t* Qlo,
                                   ushort_t* Khi, ushort_t* Klo,
                                   ushort_t* Vt) {
    int which = n >> 9, hd = n & 511;
    int head = hd >> 6, d = hd & 63;
    int hb = head * BATCH + (m_base >> 10);
    int l  = m_base & 1023;
    if (pew) {
#pragma unroll
        for (int r = 0; r < 4; r++) a[r] += pew[(size_t)(l + r) * 1536 + n];
    }
    if (which == 2) {
        ushort4 pk = make_ushort4(f2bf(a[0]), f2bf(a[1]), f2bf(a[2]), f2bf(a[3]));
        *(ushort4*)(Vt + ((size_t)hb * D_HEAD + d) * SEQ + l) = pk;
    } else {
        ushort_t* H = (which == 0) ? Qhi : Khi;
        ushort_t* L = (which == 0) ? Qlo : Klo;
#pragma unroll
        for (int r = 0; r < 4; r++) {
            float v = a[r];
            ushort_t hv = f2bf(v);
            size_t off = ((size_t)hb * SEQ + l + r) * D_HEAD + d;
            H[off] = hv;
            L[off] = f2bf(v - bf2f(hv));
        }
    }
}

// ---------------------------------------------------------------- MFMA GEMM
// C[M,N] = A[M,K] @ Bt[N,K]^T ; A,Bt bf16 row-major, acc fp32.
// Block: 256 thr = 4 waves (2x2), tile 64x64 (128-tiles regressed: grid too
// small to hide barriers — R10). launch_bounds(256,4): 4 blocks/CU for
// latency hiding (these kernels are barrier-bound, not FLOP-bound).
// MODE 0: (+pew) qkv_scatter  MODE 1: +bias, relu, bf16 out  MODE 2: +bias, fp32 out
template<int MODE, int TM, int TN>
__global__ __launch_bounds__(256, 4)
void gemm_kernel(const ushort_t* __restrict__ A, const ushort_t* __restrict__ Bt,
                 const float* __restrict__ bias, const float* __restrict__ pew,
                 float* __restrict__ outF, ushort_t* __restrict__ outB,
                 ushort_t* __restrict__ Qhi, ushort_t* __restrict__ Qlo,
                 ushort_t* __restrict__ Khi, ushort_t* __restrict__ Klo,
                 ushort_t* __restrict__ Vt,
                 int M, int N, int K) {
    constexpr int WM = TM / 2, WN = TN / 2;
    constexpr int MT = WM / 16, NT = WN / 16;
    __shared__ ushort_t As[TM][72];   // +8 pad: keeps 16B align, breaks bank alias
    __shared__ ushort_t Bs[TN][72];
    const int tid = threadIdx.x;
    const int m0 = blockIdx.y * TM, n0 = blockIdx.x * TN;
    const int w = tid >> 6, lane = tid & 63;
    const int wr = w >> 1, wc = w & 1;
    const int col = lane & 15, quad = lane >> 4;

    f32x4 acc[MT][NT] = {};

    for (int k0 = 0; k0 < K; k0 += 64) {
        __syncthreads();
#pragma unroll
        for (int p = 0; p < TM / 32; p++) {    // TM*8 chunk tasks
            int idx = p * 256 + tid;
            int row = idx >> 3, ch = (idx & 7) * 8;
            *(uint4*)(&As[row][ch]) =
                *(const uint4*)(A + (size_t)(m0 + row) * K + k0 + ch);
        }
#pragma unroll
        for (int p = 0; p < TN / 32; p++) {
            int idx = p * 256 + tid;
            int row = idx >> 3, ch = (idx & 7) * 8;
            *(uint4*)(&Bs[row][ch]) =
                *(const uint4*)(Bt + (size_t)(n0 + row) * K + k0 + ch);
        }
        __syncthreads();
#pragma unroll
        for (int ks = 0; ks < 64; ks += 32) {
            bf16x8 af[MT], bfr[NT];
#pragma unroll
            for (int t = 0; t < MT; t++)
                af[t] = *(const bf16x8*)(&As[wr * WM + t * 16 + col][ks + quad * 8]);
#pragma unroll
            for (int t = 0; t < NT; t++)
                bfr[t] = *(const bf16x8*)(&Bs[wc * WN + t * 16 + col][ks + quad * 8]);
#pragma unroll
            for (int mt = 0; mt < MT; mt++)
#pragma unroll
                for (int nt = 0; nt < NT; nt++)
                    acc[mt][nt] = __builtin_amdgcn_mfma_f32_16x16x32_bf16(
                        af[mt], bfr[nt], acc[mt][nt], 0, 0, 0);
        }
    }

#pragma unroll
    for (int mt = 0; mt < MT; mt++) {
#pragma unroll
        for (int nt = 0; nt < NT; nt++) {
            int n = n0 + wc * WN + nt * 16 + col;
            int m_base = m0 + wr * WM + mt * 16 + quad * 4;
            if (MODE == 0) {
                qkv_scatter(acc[mt][nt], n, m_base, pew, Qhi, Qlo, Khi, Klo, Vt);
            } else {
#pragma unroll
                for (int r = 0; r < 4; r++) {
                    int m = m_base + r;
                    float v = acc[mt][nt][r];
                    if (MODE == 1) {
                        float t = fmaxf(v + bias[n], 0.f);
                        outB[(size_t)m * N + n] = f2bf(t);
                    } else {
                        outF[(size_t)m * N + n] = v + bias[n];
                    }
                }
            }
        }
    }
}

// ---------------------------------------------------------------- hi/lo GEMM
// High-precision bf16 GEMM: A fp32 split in-kernel into hi+lo bf16; Bt
// pre-split (hi,lo). acc = Ah*Bh + Ah*Bl + Al*Bh (~1e-5 rel). fp32 out [M][N].
// Used for peW = pos_enc @ Wqkv (M=SEQ=1024).
__global__ __launch_bounds__(256, 4)
void gemm_hilo_kernel(const float* __restrict__ A,
                      const ushort_t* __restrict__ Bh,
                      const ushort_t* __restrict__ Bl,
                      float* __restrict__ outF, int M, int N, int K) {
    __shared__ ushort_t Ash[64][72];
    __shared__ ushort_t Asl[64][72];
    __shared__ ushort_t Bsh[64][72];
    __shared__ ushort_t Bsl[64][72];
    const int tid = threadIdx.x;
    const int m0 = blockIdx.y * 64, n0 = blockIdx.x * 64;
    const int w = tid >> 6, lane = tid & 63;
    const int wm = (w >> 1) * 32, wn = (w & 1) * 32;
    const int col = lane & 15, quad = lane >> 4;

    f32x4 acc[2][2] = {};

    for (int k0 = 0; k0 < K; k0 += 64) {
        __syncthreads();
#pragma unroll
        for (int p = 0; p < 4; p++) {
            int idx = p * 256 + tid;
            int row = idx >> 4, c4 = (idx & 15) * 4;
            float4 v = *(const float4*)(A + (size_t)(m0 + row) * K + k0 + c4);
            ushort_t h0 = f2bf(v.x), h1 = f2bf(v.y), h2 = f2bf(v.z), h3 = f2bf(v.w);
            *(ushort4*)(&Ash[row][c4]) = make_ushort4(h0, h1, h2, h3);
            *(ushort4*)(&Asl[row][c4]) = make_ushort4(
                f2bf(v.x - bf2f(h0)), f2bf(v.y - bf2f(h1)),
                f2bf(v.z - bf2f(h2)), f2bf(v.w - bf2f(h3)));
        }
#pragma unroll
        for (int p = 0; p < 2; p++) {
            int idx = p * 256 + tid;
            int row = idx >> 3, ch = (idx & 7) * 8;
            *(uint4*)(&Bsh[row][ch]) =
                *(const uint4*)(Bh + (size_t)(n0 + row) * K + k0 + ch);
            *(uint4*)(&Bsl[row][ch]) =
                *(const uint4*)(Bl + (size_t)(n0 + row) * K + k0 + ch);
        }
        __syncthreads();
#pragma unroll
        for (int ks = 0; ks < 64; ks += 32) {
            bf16x8 ah[2], al[2], bh[2], bl[2];
#pragma unroll
            for (int t = 0; t < 2; t++) {
                ah[t] = *(const bf16x8*)(&Ash[wm + t * 16 + col][ks + quad * 8]);
                al[t] = *(const bf16x8*)(&Asl[wm + t * 16 + col][ks + quad * 8]);
                bh[t] = *(const bf16x8*)(&Bsh[wn + t * 16 + col][ks + quad * 8]);
                bl[t] = *(const bf16x8*)(&Bsl[wn + t * 16 + col][ks + quad * 8]);
            }
#pragma unroll
            for (int mt = 0; mt < 2; mt++)
#pragma unroll
                for (int nt = 0; nt < 2; nt++) {
                    acc[mt][nt] = __builtin_amdgcn_mfma_f32_16x16x32_bf16(
                        ah[mt], bh[nt], acc[mt][nt], 0, 0, 0);
                    acc[mt][nt] = __builtin_amdgcn_mfma_f32_16x16x32_bf16(
                        ah[mt], bl[nt], acc[mt][nt], 0, 0, 0);
                    acc[mt][nt] = __builtin_amdgcn_mfma_f32_16x16x32_bf16(
                        al[mt], bh[nt], acc[mt][nt], 0, 0, 0);
                }
        }
    }

#pragma unroll
    for (int mt = 0; mt < 2; mt++)
#pragma unroll
        for (int nt = 0; nt < 2; nt++) {
            int n = n0 + wn + nt * 16 + col;
#pragma unroll
            for (int r = 0; r < 4; r++) {
                int m = m0 + wm + mt * 16 + quad * 4 + r;
                outF[(size_t)m * N + n] = acc[mt][nt][r];
            }
        }
}

// ---------------------------------------------------------------- attention
// MFMA flash attention — R9-proven single-buffer structure (2 barriers/tile)
// + __threadfence_block() between P write and P read (TBAA fence; confirmed
// by R11: dbuf+fence passed but regressed via LDS-doubling, so single-buffer
// is the keeper). Block = 64 Q-rows of one (b,h).
// XCD swizzle: all 16 Q-tiles of one hb land on one XCD (K/V L2-resident).
__global__ __launch_bounds__(256, 2)
void attention_kernel(const ushort_t* __restrict__ Qhi,
                      const ushort_t* __restrict__ Qlo,
                      const ushort_t* __restrict__ Khi,
                      const ushort_t* __restrict__ Klo,
                      const ushort_t* __restrict__ Vt,
                      float* __restrict__ O) {
    const int bid = blockIdx.x;          // 512
    const int j   = bid >> 3;
    const int hb  = (bid & 7) * 4 + (j >> 4);
    const int qt  = j & 15;
    const int h = hb >> 2, b = hb & 3;
    const int tid = threadIdx.x;
    const int w = tid >> 6, lane = tid & 63;
    const int col = lane & 15, quad = lane >> 4;
    const size_t kbase = (size_t)hb * SEQ * D_HEAD;
    const size_t vbase = (size_t)hb * D_HEAD * SEQ;

    __shared__ ushort_t Kh[64][72];
    __shared__ ushort_t Kl[64][72];
    __shared__ ushort_t Vs[64][72];     // V^T tile [dim][key]
    __shared__ ushort_t Pl[4][16][68];  // per-wave P [qrow][key], stride 68

    // Q fragments hi/lo (A-layout) straight from global
    bf16x8 qh[2], ql[2];
    {
        const ushort_t* qp = Qhi + kbase + (size_t)(qt * 64 + w * 16 + col) * D_HEAD;
        const ushort_t* lp = Qlo + kbase + (size_t)(qt * 64 + w * 16 + col) * D_HEAD;
        qh[0] = *(const bf16x8*)(qp + quad * 8);
        qh[1] = *(const bf16x8*)(qp + 32 + quad * 8);
        ql[0] = *(const bf16x8*)(lp + quad * 8);
        ql[1] = *(const bf16x8*)(lp + 32 + quad * 8);
    }

    f32x4 acco[4] = {};
    float mrun[4], lrun[4];
#pragma unroll
    for (int r = 0; r < 4; r++) { mrun[r] = -1e30f; lrun[r] = 0.f; }
    const float inv_temper = 0.04419417382415922f;  // 1/sqrt(512)

    for (int t0 = 0; t0 < SEQ; t0 += 64) {
        __syncthreads();   // prev tile's reads done before restage
#pragma unroll
        for (int p = 0; p < 2; p++) {
            int idx = p * 256 + tid;          // 512 tasks: 64 rows x 8 chunks
            int row = idx >> 3, ch = (idx & 7) * 8;
            *(uint4*)(&Kh[row][ch]) =
                *(const uint4*)(Khi + kbase + (size_t)(t0 + row) * D_HEAD + ch);
            *(uint4*)(&Kl[row][ch]) =
                *(const uint4*)(Klo + kbase + (size_t)(t0 + row) * D_HEAD + ch);
            *(uint4*)(&Vs[row][ch]) =
                *(const uint4*)(Vt + vbase + (size_t)row * SEQ + t0 + ch);
        }
        __syncthreads();

        // S = Q K^T (hi/lo), keys nt*16+col, rows quad*4+r
        float sc[4][4];
#pragma unroll
        for (int nt = 0; nt < 4; nt++) {
            bf16x8 bh0 = *(const bf16x8*)(&Kh[nt * 16 + col][quad * 8]);
            bf16x8 bh1 = *(const bf16x8*)(&Kh[nt * 16 + col][32 + quad * 8]);
            bf16x8 bl0 = *(const bf16x8*)(&Kl[nt * 16 + col][quad * 8]);
            bf16x8 bl1 = *(const bf16x8*)(&Kl[nt * 16 + col][32 + quad * 8]);
            f32x4 s = {};
            s = __builtin_amdgcn_mfma_f32_16x16x32_bf16(qh[0], bh0, s, 0, 0, 0);
            s = __builtin_amdgcn_mfma_f32_16x16x32_bf16(qh[1], bh1, s, 0, 0, 0);
            s = __builtin_amdgcn_mfma_f32_16x16x32_bf16(qh[0], bl0, s, 0, 0, 0);
            s = __builtin_amdgcn_mfma_f32_16x16x32_bf16(qh[1], bl1, s, 0, 0, 0);
            s = __builtin_amdgcn_mfma_f32_16x16x32_bf16(ql[0], bh0, s, 0, 0, 0);
            s = __builtin_amdgcn_mfma_f32_16x16x32_bf16(ql[1], bh1, s, 0, 0, 0);
#pragma unroll
            for (int r = 0; r < 4; r++) sc[nt][r] = s[r] * inv_temper;
        }

        // online softmax: row stats via quad shfl_xor reductions
        float tmax[4];
#pragma unroll
        for (int r = 0; r < 4; r++)
            tmax[r] = fmaxf(fmaxf(sc[0][r], sc[1][r]), fmaxf(sc[2][r], sc[3][r]));
#pragma unroll
        for (int mask = 1; mask < 16; mask <<= 1)
#pragma unroll
            for (int r = 0; r < 4; r++)
                tmax[r] = fmaxf(tmax[r], __shfl_xor(tmax[r], mask, 64));

        float alpha[4], tsum[4];
#pragma unroll
        for (int r = 0; r < 4; r++) {
            float mn = fmaxf(mrun[r], tmax[r]);
            alpha[r] = __expf(mrun[r] - mn);
            mrun[r] = mn;
            tsum[r] = 0.f;
        }
#pragma unroll
        for (int nt = 0; nt < 4; nt++)
#pragma unroll
            for (int r = 0; r < 4; r++) {
                float pv = __expf(sc[nt][r] - mrun[r]);
                tsum[r] += pv;
                Pl[w][quad * 4 + r][nt * 16 + col] = f2bf(pv);
            }
#pragma unroll
        for (int mask = 1; mask < 16; mask <<= 1)
#pragma unroll
            for (int r = 0; r < 4; r++)
                tsum[r] += __shfl_xor(tsum[r], mask, 64);
#pragma unroll
        for (int r = 0; r < 4; r++)
            lrun[r] = lrun[r] * alpha[r] + tsum[r];
#pragma unroll
        for (int nt = 0; nt < 4; nt++)
#pragma unroll
            for (int r = 0; r < 4; r++)
                acco[nt][r] *= alpha[r];

        // Order the Pl stores before the type-punned reads below (wave-local
        // visibility; also a compiler fence against TBAA reordering).
        __threadfence_block();

        // P (A-layout) and PV
        union { ulong2 u; bf16x8 v; } a0, a1;
        a0.u.x = *(const ull_t*)(&Pl[w][col][quad * 8]);
        a0.u.y = *(const ull_t*)(&Pl[w][col][quad * 8 + 4]);
        a1.u.x = *(const ull_t*)(&Pl[w][col][32 + quad * 8]);
        a1.u.y = *(const ull_t*)(&Pl[w][col][32 + quad * 8 + 4]);
#pragma unroll
        for (int nt = 0; nt < 4; nt++) {
            bf16x8 bv0 = *(const bf16x8*)(&Vs[nt * 16 + col][quad * 8]);
            bf16x8 bv1 = *(const bf16x8*)(&Vs[nt * 16 + col][32 + quad * 8]);
            acco[nt] = __builtin_amdgcn_mfma_f32_16x16x32_bf16(a0.v, bv0, acco[nt], 0, 0, 0);
            acco[nt] = __builtin_amdgcn_mfma_f32_16x16x32_bf16(a1.v, bv1, acco[nt], 0, 0, 0);
        }
    }

    // epilogue: O[b][row][h*64 + dim], dim = nt*16+col, row = qt*64+w*16+quad*4+r
#pragma unroll
    for (int nt = 0; nt < 4; nt++) {
#pragma unroll
        for (int r = 0; r < 4; r++) {
            int row = qt * 64 + w * 16 + quad * 4 + r;
            O[((size_t)b * SEQ + row) * D_MODEL + h * D_HEAD + nt * 16 + col]
                = acco[nt][r] / lrun[r];
        }
    }
}

// ---------------------------------------------------------------- add + LN
__device__ inline float block_sum_256(float v, float* tmp) {
#pragma unroll
    for (int off = 32; off > 0; off >>= 1) v += __shfl_down(v, off, 64);
    if ((threadIdx.x & 63) == 0) tmp[threadIdx.x >> 6] = v;
    __syncthreads();
    return tmp[0] + tmp[1] + tmp[2] + tmp[3];
}

// Writes fp32 Out AND bf16 OutBf. Safe for Out==R (in-place).
__global__ void add_norm_kernel(const float* __restrict__ A,
                                const float* __restrict__ R,
                                const float* __restrict__ ga,
                                const float* __restrict__ gb,
                                float* __restrict__ Out,
                                ushort_t* __restrict__ OutBf) {
    int tok = blockIdx.x, tid = threadIdx.x;
    __shared__ float t1[4], t2[4];
    size_t base = (size_t)tok * D_MODEL;
    float z0 = A[base + tid]       + R[base + tid];
    float z1 = A[base + tid + 256] + R[base + tid + 256];
    float s = block_sum_256(z0 + z1, t1);
    float mu = s * (1.f / (float)D_MODEL);
    float d0 = z0 - mu, d1 = z1 - mu;
    float ss = block_sum_256(d0 * d0 + d1 * d1, t2);
    float sigma = sqrtf(ss * (1.f / (float)(D_MODEL - 1)));
    float inv = 1.f / (sigma + LN_EPS);
    float r0 = d0 * inv * ga[tid]       + gb[tid];
    float r1 = d1 * inv * ga[tid + 256] + gb[tid + 256];
    Out[base + tid]         = r0;
    Out[base + tid + 256]   = r1;
    OutBf[base + tid]       = f2bf(r0);
    OutBf[base + tid + 256] = f2bf(r1);
}

// ---------------------------------------------------------------- launch
extern "C" void kernel_launch(void* const* d_in, const int* in_sizes, int n_in,
                              void* d_out, int out_size, void* d_ws, size_t ws_size,
                              hipStream_t stream) {
    const float* x     = (const float*)d_in[0];
    const float* pe    = (const float*)d_in[1];
    const float* w_qs  = (const float*)d_in[2];
    const float* w_ks  = (const float*)d_in[3];
    const float* w_vs  = (const float*)d_in[4];
    const float* ln1_a = (const float*)d_in[5];
    const float* ln1_b = (const float*)d_in[6];
    const float* w1    = (const float*)d_in[7];
    const float* b1    = (const float*)d_in[8];
    const float* w2    = (const float*)d_in[9];
    const float* b2    = (const float*)d_in[10];
    const float* ln2_a = (const float*)d_in[11];
    const float* ln2_b = (const float*)d_in[12];
    float* out = (float*)d_out;

    const size_t NXD = (size_t)NTOK * D_MODEL;       // 2M elements
    char* p = (char*)d_ws;
    float*    X    = (float*)p;     p += NXD * 4;                 // 8 MB
    float*    Ob   = (float*)p;     p += NXD * 4;                 // 8 MB
    ushort_t* Xbf  = (ushort_t*)p;  p += NXD * 2;                 // 4 MB
    ushort_t* Xraw = (ushort_t*)p;  p += NXD * 2;                 // 4 MB  bf16(x)
    ushort_t* Qhi  = (ushort_t*)p;  p += NXD * 2;                 // 4 MB
    ushort_t* Qlo  = (ushort_t*)p;  p += NXD * 2;                 // 4 MB
    ushort_t* Khi  = (ushort_t*)p;  p += NXD * 2;                 // 4 MB
    ushort_t* Klo  = (ushort_t*)p;  p += NXD * 2;                 // 4 MB
    ushort_t* Vt   = (ushort_t*)p;  p += NXD * 2;                 // 4 MB
    ushort_t* Wqkv = (ushort_t*)p;  p += (size_t)N_LAYERS * 1536 * 512 * 2;  // 3 MB (hi)
    ushort_t* WqkvL= (ushort_t*)p;  p += (size_t)1536 * 512 * 2;  // 1.5 MB (lo, layer 0)
    ushort_t* W1b  = (ushort_t*)p;  p += (size_t)N_LAYERS * D_INNER * D_MODEL * 2;  // 2 MB
    ushort_t* W2b  = (ushort_t*)p;  /* 2 MB */
    // Aliases (stream-ordered safe):
    //  H (bf16, 8 MB) = Qhi+Qlo: Q dead after attention; H consumed by FFN2
    //  before next layer's QKV GEMM rewrites Q.
    //  PEW (fp32 [1024][1536], 6 MB) = Ob: produced+consumed before attention
    //  writes Ob in layer 1; unused afterwards.
    ushort_t* Hbf  = Qhi;
    float*    PEW  = Ob;

    add_pos_kernel<<<(int)(NXD / 256), 256, 0, stream>>>(x, pe, X, Xraw);

    for (int i = 0; i < N_LAYERS; i++) {
        conv_qkvw_kernel<<<1536 * 512 / 256, 256, 0, stream>>>(
            w_qs + (size_t)i * N_HEAD * D_MODEL * D_HEAD,
            w_ks + (size_t)i * N_HEAD * D_MODEL * D_HEAD,
            w_vs + (size_t)i * N_HEAD * D_MODEL * D_HEAD,
            Wqkv + (size_t)i * 1536 * 512,
            (i == 0) ? WqkvL : (ushort_t*)nullptr);
    }
    conv_bf16_kernel<<<(N_LAYERS * D_INNER * D_MODEL) / 256, 256, 0, stream>>>(
        w1, W1b, N_LAYERS * D_INNER * D_MODEL);
    conv_bf16_kernel<<<(N_LAYERS * D_MODEL * D_INNER) / 256, 256, 0, stream>>>(
        w2, W2b, N_LAYERS * D_MODEL * D_INNER);

    for (int i = 0; i < N_LAYERS; i++) {
        if (i == 0) {
            // peW = pe @ Wqkv, fp32-accurate (hi/lo), M=1024 (batch-invariant)
            gemm_hilo_kernel<<<dim3(1536 / 64, SEQ / 64), 256, 0, stream>>>(
                pe, Wqkv, WqkvL, PEW, SEQ, 1536, D_MODEL);
            // QKV = xW (plain bf16) + peW (epilogue add) -> hi/lo scatter
            gemm_kernel<0, 64, 64><<<dim3(1536 / 64, NTOK / 64), 256, 0, stream>>>(
                Xraw, Wqkv, nullptr, PEW, nullptr, nullptr,
                Qhi, Qlo, Khi, Klo, Vt, NTOK, 1536, D_MODEL);
        } else {
            gemm_kernel<0, 64, 64><<<dim3(1536 / 64, NTOK / 64), 256, 0, stream>>>(
                Xbf, Wqkv + (size_t)i * 1536 * 512, nullptr, nullptr, nullptr,
                nullptr, Qhi, Qlo, Khi, Klo, Vt, NTOK, 1536, D_MODEL);
        }

        attention_kernel<<<512, 256, 0, stream>>>(Qhi, Qlo, Khi, Klo, Vt, Ob);

        add_norm_kernel<<<NTOK, 256, 0, stream>>>(
            Ob, X, ln1_a + i * D_MODEL, ln1_b + i * D_MODEL, X, Xbf);

        // FFN1: M=4096, N=1024, K=512, bias+relu -> bf16 H (aliases Qhi/Qlo)
        gemm_kernel<1, 64, 64><<<dim3(D_INNER / 64, NTOK / 64), 256, 0, stream>>>(
            Xbf, W1b + (size_t)i * D_INNER * D_MODEL, b1 + (size_t)i * D_INNER,
            nullptr, nullptr, Hbf, nullptr, nullptr, nullptr, nullptr, nullptr,
            NTOK, D_INNER, D_MODEL);

        // FFN2: M=4096, N=512, K=1024, bias -> fp32 Ob
        gemm_kernel<2, 64, 64><<<dim3(D_MODEL / 64, NTOK / 64), 256, 0, stream>>>(
            Hbf, W2b + (size_t)i * D_MODEL * D_INNER, b2 + (size_t)i * D_MODEL,
            nullptr, Ob, nullptr, nullptr, nullptr, nullptr, nullptr, nullptr,
            NTOK, D_MODEL, D_INNER);

        float* dst = (i == N_LAYERS - 1) ? out : X;
        add_norm_kernel<<<NTOK, 256, 0, stream>>>(
            Ob, X, ln2_a + i * D_MODEL, ln2_b + i * D_MODEL, dst, Xbf);
    }
}

// Round 14
// 369.019 us; speedup vs baseline: 1.1133x; 1.0478x over previous
//
#include <hip/hip_runtime.h>
#include <math.h>

#define D_MODEL 512
#define SEQ     1024
#define BATCH   4
#define N_LAYERS 2
#define N_HEAD  8
#define D_HEAD  64
#define D_INNER 1024
#define NTOK    (BATCH*SEQ)   // 4096
#define LN_EPS  1e-3f

typedef float f32x4 __attribute__((ext_vector_type(4)));
typedef short bf16x8 __attribute__((ext_vector_type(8)));
typedef unsigned short ushort_t;
typedef unsigned int uint_t;
typedef unsigned long long ull_t;

// fp32 -> bf16 round-to-nearest-even
__device__ inline ushort_t f2bf(float f) {
    uint_t u = __float_as_uint(f);
    u += 0x7FFFu + ((u >> 16) & 1u);
    return (ushort_t)(u >> 16);
}
__device__ inline float bf2f(ushort_t h) {
    return __uint_as_float((uint_t)h << 16);
}

// ---------------------------------------------------------------- add pos enc
// X = x + pe (fp32 residual path); Xrawbf = bf16(x) (layer-1 xW GEMM input)
__global__ void add_pos_kernel(const float* __restrict__ x,
                               const float* __restrict__ pe,
                               float* __restrict__ X,
                               ushort_t* __restrict__ Xrawbf) {
    int idx = blockIdx.x * blockDim.x + threadIdx.x;   // over NTOK*D_MODEL
    int l = (idx / D_MODEL) % SEQ;
    int d = idx % D_MODEL;
    float xv = x[idx];
    X[idx] = xv + pe[l * D_MODEL + d];
    Xrawbf[idx] = f2bf(xv);
}

// ---------------------------------------------------------------- weight conv
__global__ void conv_bf16_kernel(const float* __restrict__ src,
                                 ushort_t* __restrict__ dst, int n) {
    int idx = blockIdx.x * 256 + threadIdx.x;
    if (idx < n) dst[idx] = f2bf(src[idx]);
}

// Pack per-layer QKV weights into Bt layout [1536][512] (hi, optional lo):
// row n: which=n>>9, h=(n>>6)&7, d=n&63 ; Bt[n][k] = W_which[h][k][d]
__global__ void conv_qkvw_kernel(const float* __restrict__ wq,
                                 const float* __restrict__ wk,
                                 const float* __restrict__ wv,
                                 ushort_t* __restrict__ hi,
                                 ushort_t* __restrict__ lo) {
    int idx = blockIdx.x * 256 + threadIdx.x;   // over 1536*512
    int n = idx >> 9, k = idx & 511;
    int which = n >> 9, h = (n >> 6) & 7, d = n & 63;
    const float* W = (which == 0) ? wq : (which == 1) ? wk : wv;
    float v = W[((size_t)h * D_MODEL + k) * D_HEAD + d];
    ushort_t hv = f2bf(v);
    hi[idx] = hv;
    if (lo) lo[idx] = f2bf(v - bf2f(hv));
}

// ---------------------------------------------------------------- QKV scatter
// n in [0,1536): which=n>>9 (0:Q 1:K 2:V), head=(n>>6)&7, d=n&63.
// Optional pew add (layer 1): acc += peW[l][n], broadcast over batch.
// Q,K -> hi/lo bf16 [hb][seq][64]; V -> bf16 transposed [hb][dim][seq].
__device__ inline void qkv_scatter(f32x4 a, int n, int m_base,
                                   const float* __restrict__ pew,
                                   ushort_t* Qhi, ushort_t* Qlo,
                                   ushort_t* Khi, ushort_t* Klo,
                                   ushort_t* Vt) {
    int which = n >> 9, hd = n & 511;
    int head = hd >> 6, d = hd & 63;
    int hb = head * BATCH + (m_base >> 10);
    int l  = m_base & 1023;
    if (pew) {
#pragma unroll
        for (int r = 0; r < 4; r++) a[r] += pew[(size_t)(l + r) * 1536 + n];
    }
    if (which == 2) {
        ushort4 pk = make_ushort4(f2bf(a[0]), f2bf(a[1]), f2bf(a[2]), f2bf(a[3]));
        *(ushort4*)(Vt + ((size_t)hb * D_HEAD + d) * SEQ + l) = pk;
    } else {
        ushort_t* H = (which == 0) ? Qhi : Khi;
        ushort_t* L = (which == 0) ? Qlo : Klo;
#pragma unroll
        for (int r = 0; r < 4; r++) {
            float v = a[r];
            ushort_t hv = f2bf(v);
            size_t off = ((size_t)hb * SEQ + l + r) * D_HEAD + d;
            H[off] = hv;
            L[off] = f2bf(v - bf2f(hv));
        }
    }
}

// ---------------------------------------------------------------- MFMA GEMM
// C[M,N] = A[M,K] @ Bt[N,K]^T ; A,Bt bf16 row-major, acc fp32.
// Block: 256 thr = 4 waves (2x2), tile 64x64 (128-tiles regressed: grid too
// small to hide barriers — R10; launch_bounds(256,4) neutral — R12).
// MODE 0: (+pew) qkv_scatter  MODE 1: +bias, relu, bf16 out  MODE 2: +bias, fp32 out
template<int MODE, int TM, int TN>
__global__ __launch_bounds__(256, 4)
void gemm_kernel(const ushort_t* __restrict__ A, const ushort_t* __restrict__ Bt,
                 const float* __restrict__ bias, const float* __restrict__ pew,
                 float* __restrict__ outF, ushort_t* __restrict__ outB,
                 ushort_t* __restrict__ Qhi, ushort_t* __restrict__ Qlo,
                 ushort_t* __restrict__ Khi, ushort_t* __restrict__ Klo,
                 ushort_t* __restrict__ Vt,
                 int M, int N, int K) {
    constexpr int WM = TM / 2, WN = TN / 2;
    constexpr int MT = WM / 16, NT = WN / 16;
    __shared__ ushort_t As[TM][72];   // +8 pad: keeps 16B align, breaks bank alias
    __shared__ ushort_t Bs[TN][72];
    const int tid = threadIdx.x;
    const int m0 = blockIdx.y * TM, n0 = blockIdx.x * TN;
    const int w = tid >> 6, lane = tid & 63;
    const int wr = w >> 1, wc = w & 1;
    const int col = lane & 15, quad = lane >> 4;

    f32x4 acc[MT][NT] = {};

    for (int k0 = 0; k0 < K; k0 += 64) {
        __syncthreads();
#pragma unroll
        for (int p = 0; p < TM / 32; p++) {    // TM*8 chunk tasks
            int idx = p * 256 + tid;
            int row = idx >> 3, ch = (idx & 7) * 8;
            *(uint4*)(&As[row][ch]) =
                *(const uint4*)(A + (size_t)(m0 + row) * K + k0 + ch);
        }
#pragma unroll
        for (int p = 0; p < TN / 32; p++) {
            int idx = p * 256 + tid;
            int row = idx >> 3, ch = (idx & 7) * 8;
            *(uint4*)(&Bs[row][ch]) =
                *(const uint4*)(Bt + (size_t)(n0 + row) * K + k0 + ch);
        }
        __syncthreads();
#pragma unroll
        for (int ks = 0; ks < 64; ks += 32) {
            bf16x8 af[MT], bfr[NT];
#pragma unroll
            for (int t = 0; t < MT; t++)
                af[t] = *(const bf16x8*)(&As[wr * WM + t * 16 + col][ks + quad * 8]);
#pragma unroll
            for (int t = 0; t < NT; t++)
                bfr[t] = *(const bf16x8*)(&Bs[wc * WN + t * 16 + col][ks + quad * 8]);
#pragma unroll
            for (int mt = 0; mt < MT; mt++)
#pragma unroll
                for (int nt = 0; nt < NT; nt++)
                    acc[mt][nt] = __builtin_amdgcn_mfma_f32_16x16x32_bf16(
                        af[mt], bfr[nt], acc[mt][nt], 0, 0, 0);
        }
    }

#pragma unroll
    for (int mt = 0; mt < MT; mt++) {
#pragma unroll
        for (int nt = 0; nt < NT; nt++) {
            int n = n0 + wc * WN + nt * 16 + col;
            int m_base = m0 + wr * WM + mt * 16 + quad * 4;
            if (MODE == 0) {
                qkv_scatter(acc[mt][nt], n, m_base, pew, Qhi, Qlo, Khi, Klo, Vt);
            } else {
#pragma unroll
                for (int r = 0; r < 4; r++) {
                    int m = m_base + r;
                    float v = acc[mt][nt][r];
                    if (MODE == 1) {
                        float t = fmaxf(v + bias[n], 0.f);
                        outB[(size_t)m * N + n] = f2bf(t);
                    } else {
                        outF[(size_t)m * N + n] = v + bias[n];
                    }
                }
            }
        }
    }
}

// ---------------------------------------------------------------- hi/lo GEMM
// High-precision bf16 GEMM: A fp32 split in-kernel into hi+lo bf16; Bt
// pre-split (hi,lo). acc = Ah*Bh + Ah*Bl + Al*Bh (~1e-5 rel). fp32 out [M][N].
// Used for peW = pos_enc @ Wqkv (M=SEQ=1024).
__global__ __launch_bounds__(256, 4)
void gemm_hilo_kernel(const float* __restrict__ A,
                      const ushort_t* __restrict__ Bh,
                      const ushort_t* __restrict__ Bl,
                      float* __restrict__ outF, int M, int N, int K) {
    __shared__ ushort_t Ash[64][72];
    __shared__ ushort_t Asl[64][72];
    __shared__ ushort_t Bsh[64][72];
    __shared__ ushort_t Bsl[64][72];
    const int tid = threadIdx.x;
    const int m0 = blockIdx.y * 64, n0 = blockIdx.x * 64;
    const int w = tid >> 6, lane = tid & 63;
    const int wm = (w >> 1) * 32, wn = (w & 1) * 32;
    const int col = lane & 15, quad = lane >> 4;

    f32x4 acc[2][2] = {};

    for (int k0 = 0; k0 < K; k0 += 64) {
        __syncthreads();
#pragma unroll
        for (int p = 0; p < 4; p++) {
            int idx = p * 256 + tid;
            int row = idx >> 4, c4 = (idx & 15) * 4;
            float4 v = *(const float4*)(A + (size_t)(m0 + row) * K + k0 + c4);
            ushort_t h0 = f2bf(v.x), h1 = f2bf(v.y), h2 = f2bf(v.z), h3 = f2bf(v.w);
            *(ushort4*)(&Ash[row][c4]) = make_ushort4(h0, h1, h2, h3);
            *(ushort4*)(&Asl[row][c4]) = make_ushort4(
                f2bf(v.x - bf2f(h0)), f2bf(v.y - bf2f(h1)),
                f2bf(v.z - bf2f(h2)), f2bf(v.w - bf2f(h3)));
        }
#pragma unroll
        for (int p = 0; p < 2; p++) {
            int idx = p * 256 + tid;
            int row = idx >> 3, ch = (idx & 7) * 8;
            *(uint4*)(&Bsh[row][ch]) =
                *(const uint4*)(Bh + (size_t)(n0 + row) * K + k0 + ch);
            *(uint4*)(&Bsl[row][ch]) =
                *(const uint4*)(Bl + (size_t)(n0 + row) * K + k0 + ch);
        }
        __syncthreads();
#pragma unroll
        for (int ks = 0; ks < 64; ks += 32) {
            bf16x8 ah[2], al[2], bh[2], bl[2];
#pragma unroll
            for (int t = 0; t < 2; t++) {
                ah[t] = *(const bf16x8*)(&Ash[wm + t * 16 + col][ks + quad * 8]);
                al[t] = *(const bf16x8*)(&Asl[wm + t * 16 + col][ks + quad * 8]);
                bh[t] = *(const bf16x8*)(&Bsh[wn + t * 16 + col][ks + quad * 8]);
                bl[t] = *(const bf16x8*)(&Bsl[wn + t * 16 + col][ks + quad * 8]);
            }
#pragma unroll
            for (int mt = 0; mt < 2; mt++)
#pragma unroll
                for (int nt = 0; nt < 2; nt++) {
                    acc[mt][nt] = __builtin_amdgcn_mfma_f32_16x16x32_bf16(
                        ah[mt], bh[nt], acc[mt][nt], 0, 0, 0);
                    acc[mt][nt] = __builtin_amdgcn_mfma_f32_16x16x32_bf16(
                        ah[mt], bl[nt], acc[mt][nt], 0, 0, 0);
                    acc[mt][nt] = __builtin_amdgcn_mfma_f32_16x16x32_bf16(
                        al[mt], bh[nt], acc[mt][nt], 0, 0, 0);
                }
        }
    }

#pragma unroll
    for (int mt = 0; mt < 2; mt++)
#pragma unroll
        for (int nt = 0; nt < 2; nt++) {
            int n = n0 + wn + nt * 16 + col;
#pragma unroll
            for (int r = 0; r < 4; r++) {
                int m = m0 + wm + mt * 16 + quad * 4 + r;
                outF[(size_t)m * N + n] = acc[mt][nt][r];
            }
        }
}

// ---------------------------------------------------------------- attention
// MFMA flash attention — R9-proven single-buffer structure (2 barriers/tile)
// + TBAA fence before the P round-trip read. Template HILO: layer 1 needs
// fp32-accurate scores (hi/lo K and Q, 6 MFMAs); layer 2's LN'd inputs give
// score spread ~0.07 with bf16 error ~1e-4 — plain bf16 (4 MFMAs, skip Kl).
// Block = 64 Q-rows of one (b,h); XCD swizzle keeps each hb on one XCD.
template<bool HILO>
__global__ __launch_bounds__(256, 2)
void attention_kernel(const ushort_t* __restrict__ Qhi,
                      const ushort_t* __restrict__ Qlo,
                      const ushort_t* __restrict__ Khi,
                      const ushort_t* __restrict__ Klo,
                      const ushort_t* __restrict__ Vt,
                      float* __restrict__ O) {
    const int bid = blockIdx.x;          // 512
    const int j   = bid >> 3;
    const int hb  = (bid & 7) * 4 + (j >> 4);
    const int qt  = j & 15;
    const int h = hb >> 2, b = hb & 3;
    const int tid = threadIdx.x;
    const int w = tid >> 6, lane = tid & 63;
    const int col = lane & 15, quad = lane >> 4;
    const size_t kbase = (size_t)hb * SEQ * D_HEAD;
    const size_t vbase = (size_t)hb * D_HEAD * SEQ;

    __shared__ ushort_t Kh[64][72];
    __shared__ ushort_t Kl[HILO ? 64 : 1][72];
    __shared__ ushort_t Vs[64][72];     // V^T tile [dim][key]
    __shared__ ushort_t Pl[4][16][68];  // per-wave P [qrow][key], stride 68

    // Q fragments (A-layout) straight from global; lo only when HILO
    bf16x8 qh[2], ql[2];
    {
        const ushort_t* qp = Qhi + kbase + (size_t)(qt * 64 + w * 16 + col) * D_HEAD;
        qh[0] = *(const bf16x8*)(qp + quad * 8);
        qh[1] = *(const bf16x8*)(qp + 32 + quad * 8);
        if (HILO) {
            const ushort_t* lp = Qlo + kbase + (size_t)(qt * 64 + w * 16 + col) * D_HEAD;
            ql[0] = *(const bf16x8*)(lp + quad * 8);
            ql[1] = *(const bf16x8*)(lp + 32 + quad * 8);
        }
    }

    f32x4 acco[4] = {};
    float mrun[4], lrun[4];
#pragma unroll
    for (int r = 0; r < 4; r++) { mrun[r] = -1e30f; lrun[r] = 0.f; }
    const float inv_temper = 0.04419417382415922f;  // 1/sqrt(512)

    for (int t0 = 0; t0 < SEQ; t0 += 64) {
        __syncthreads();   // prev tile's reads done before restage
#pragma unroll
        for (int p = 0; p < 2; p++) {
            int idx = p * 256 + tid;          // 512 tasks: 64 rows x 8 chunks
            int row = idx >> 3, ch = (idx & 7) * 8;
            *(uint4*)(&Kh[row][ch]) =
                *(const uint4*)(Khi + kbase + (size_t)(t0 + row) * D_HEAD + ch);
            if (HILO)
                *(uint4*)(&Kl[row][ch]) =
                    *(const uint4*)(Klo + kbase + (size_t)(t0 + row) * D_HEAD + ch);
            *(uint4*)(&Vs[row][ch]) =
                *(const uint4*)(Vt + vbase + (size_t)row * SEQ + t0 + ch);
        }
        __syncthreads();

        // S = Q K^T, keys nt*16+col, rows quad*4+r
        float sc[4][4];
#pragma unroll
        for (int nt = 0; nt < 4; nt++) {
            bf16x8 bh0 = *(const bf16x8*)(&Kh[nt * 16 + col][quad * 8]);
            bf16x8 bh1 = *(const bf16x8*)(&Kh[nt * 16 + col][32 + quad * 8]);
            f32x4 s = {};
            s = __builtin_amdgcn_mfma_f32_16x16x32_bf16(qh[0], bh0, s, 0, 0, 0);
            s = __builtin_amdgcn_mfma_f32_16x16x32_bf16(qh[1], bh1, s, 0, 0, 0);
            if (HILO) {
                bf16x8 bl0 = *(const bf16x8*)(&Kl[nt * 16 + col][quad * 8]);
                bf16x8 bl1 = *(const bf16x8*)(&Kl[nt * 16 + col][32 + quad * 8]);
                s = __builtin_amdgcn_mfma_f32_16x16x32_bf16(qh[0], bl0, s, 0, 0, 0);
                s = __builtin_amdgcn_mfma_f32_16x16x32_bf16(qh[1], bl1, s, 0, 0, 0);
                s = __builtin_amdgcn_mfma_f32_16x16x32_bf16(ql[0], bh0, s, 0, 0, 0);
                s = __builtin_amdgcn_mfma_f32_16x16x32_bf16(ql[1], bh1, s, 0, 0, 0);
            }
#pragma unroll
            for (int r = 0; r < 4; r++) sc[nt][r] = s[r] * inv_temper;
        }

        // online softmax: row stats via quad shfl_xor reductions
        float tmax[4];
#pragma unroll
        for (int r = 0; r < 4; r++)
            tmax[r] = fmaxf(fmaxf(sc[0][r], sc[1][r]), fmaxf(sc[2][r], sc[3][r]));
#pragma unroll
        for (int mask = 1; mask < 16; mask <<= 1)
#pragma unroll
            for (int r = 0; r < 4; r++)
                tmax[r] = fmaxf(tmax[r], __shfl_xor(tmax[r], mask, 64));

        float alpha[4], tsum[4];
#pragma unroll
        for (int r = 0; r < 4; r++) {
            float mn = fmaxf(mrun[r], tmax[r]);
            alpha[r] = __expf(mrun[r] - mn);
            mrun[r] = mn;
            tsum[r] = 0.f;
        }
#pragma unroll
        for (int nt = 0; nt < 4; nt++)
#pragma unroll
            for (int r = 0; r < 4; r++) {
                float pv = __expf(sc[nt][r] - mrun[r]);
                tsum[r] += pv;
                Pl[w][quad * 4 + r][nt * 16 + col] = f2bf(pv);
            }
#pragma unroll
        for (int mask = 1; mask < 16; mask <<= 1)
#pragma unroll
            for (int r = 0; r < 4; r++)
                tsum[r] += __shfl_xor(tsum[r], mask, 64);
#pragma unroll
        for (int r = 0; r < 4; r++)
            lrun[r] = lrun[r] * alpha[r] + tsum[r];
#pragma unroll
        for (int nt = 0; nt < 4; nt++)
#pragma unroll
            for (int r = 0; r < 4; r++)
                acco[nt][r] *= alpha[r];

        // Order the Pl stores before the type-punned reads below (wave-local
        // visibility; also a compiler fence against TBAA reordering).
        __threadfence_block();

        // P (A-layout) and PV
        union { ulong2 u; bf16x8 v; } a0, a1;
        a0.u.x = *(const ull_t*)(&Pl[w][col][quad * 8]);
        a0.u.y = *(const ull_t*)(&Pl[w][col][quad * 8 + 4]);
        a1.u.x = *(const ull_t*)(&Pl[w][col][32 + quad * 8]);
        a1.u.y = *(const ull_t*)(&Pl[w][col][32 + quad * 8 + 4]);
#pragma unroll
        for (int nt = 0; nt < 4; nt++) {
            bf16x8 bv0 = *(const bf16x8*)(&Vs[nt * 16 + col][quad * 8]);
            bf16x8 bv1 = *(const bf16x8*)(&Vs[nt * 16 + col][32 + quad * 8]);
            acco[nt] = __builtin_amdgcn_mfma_f32_16x16x32_bf16(a0.v, bv0, acco[nt], 0, 0, 0);
            acco[nt] = __builtin_amdgcn_mfma_f32_16x16x32_bf16(a1.v, bv1, acco[nt], 0, 0, 0);
        }
    }

    // epilogue: O[b][row][h*64 + dim], dim = nt*16+col, row = qt*64+w*16+quad*4+r
#pragma unroll
    for (int nt = 0; nt < 4; nt++) {
#pragma unroll
        for (int r = 0; r < 4; r++) {
            int row = qt * 64 + w * 16 + quad * 4 + r;
            O[((size_t)b * SEQ + row) * D_MODEL + h * D_HEAD + nt * 16 + col]
                = acco[nt][r] / lrun[r];
        }
    }
}

// ---------------------------------------------------------------- add + LN
__device__ inline float block_sum_256(float v, float* tmp) {
#pragma unroll
    for (int off = 32; off > 0; off >>= 1) v += __shfl_down(v, off, 64);
    if ((threadIdx.x & 63) == 0) tmp[threadIdx.x >> 6] = v;
    __syncthreads();
    return tmp[0] + tmp[1] + tmp[2] + tmp[3];
}

// Writes fp32 Out AND bf16 OutBf. Safe for Out==R (in-place).
__global__ void add_norm_kernel(const float* __restrict__ A,
                                const float* __restrict__ R,
                                const float* __restrict__ ga,
                                const float* __restrict__ gb,
                                float* __restrict__ Out,
                                ushort_t* __restrict__ OutBf) {
    int tok = blockIdx.x, tid = threadIdx.x;
    __shared__ float t1[4], t2[4];
    size_t base = (size_t)tok * D_MODEL;
    float z0 = A[base + tid]       + R[base + tid];
    float z1 = A[base + tid + 256] + R[base + tid + 256];
    float s = block_sum_256(z0 + z1, t1);
    float mu = s * (1.f / (float)D_MODEL);
    float d0 = z0 - mu, d1 = z1 - mu;
    float ss = block_sum_256(d0 * d0 + d1 * d1, t2);
    float sigma = sqrtf(ss * (1.f / (float)(D_MODEL - 1)));
    float inv = 1.f / (sigma + LN_EPS);
    float r0 = d0 * inv * ga[tid]       + gb[tid];
    float r1 = d1 * inv * ga[tid + 256] + gb[tid + 256];
    Out[base + tid]         = r0;
    Out[base + tid + 256]   = r1;
    OutBf[base + tid]       = f2bf(r0);
    OutBf[base + tid + 256] = f2bf(r1);
}

// ---------------------------------------------------------------- launch
extern "C" void kernel_launch(void* const* d_in, const int* in_sizes, int n_in,
                              void* d_out, int out_size, void* d_ws, size_t ws_size,
                              hipStream_t stream) {
    const float* x     = (const float*)d_in[0];
    const float* pe    = (const float*)d_in[1];
    const float* w_qs  = (const float*)d_in[2];
    const float* w_ks  = (const float*)d_in[3];
    const float* w_vs  = (const float*)d_in[4];
    const float* ln1_a = (const float*)d_in[5];
    const float* ln1_b = (const float*)d_in[6];
    const float* w1    = (const float*)d_in[7];
    const float* b1    = (const float*)d_in[8];
    const float* w2    = (const float*)d_in[9];
    const float* b2    = (const float*)d_in[10];
    const float* ln2_a = (const float*)d_in[11];
    const float* ln2_b = (const float*)d_in[12];
    float* out = (float*)d_out;

    const size_t NXD = (size_t)NTOK * D_MODEL;       // 2M elements
    char* p = (char*)d_ws;
    float*    X    = (float*)p;     p += NXD * 4;                 // 8 MB
    float*    Ob   = (float*)p;     p += NXD * 4;                 // 8 MB
    ushort_t* Xbf  = (ushort_t*)p;  p += NXD * 2;                 // 4 MB
    ushort_t* Xraw = (ushort_t*)p;  p += NXD * 2;                 // 4 MB  bf16(x)
    ushort_t* Qhi  = (ushort_t*)p;  p += NXD * 2;                 // 4 MB
    ushort_t* Qlo  = (ushort_t*)p;  p += NXD * 2;                 // 4 MB
    ushort_t* Khi  = (ushort_t*)p;  p += NXD * 2;                 // 4 MB
    ushort_t* Klo  = (ushort_t*)p;  p += NXD * 2;                 // 4 MB
    ushort_t* Vt   = (ushort_t*)p;  p += NXD * 2;                 // 4 MB
    ushort_t* Wqkv = (ushort_t*)p;  p += (size_t)N_LAYERS * 1536 * 512 * 2;  // 3 MB (hi)
    ushort_t* WqkvL= (ushort_t*)p;  p += (size_t)1536 * 512 * 2;  // 1.5 MB (lo, layer 0)
    ushort_t* W1b  = (ushort_t*)p;  p += (size_t)N_LAYERS * D_INNER * D_MODEL * 2;  // 2 MB
    ushort_t* W2b  = (ushort_t*)p;  /* 2 MB */
    // Aliases (stream-ordered safe):
    //  H (bf16, 8 MB) = Qhi+Qlo: Q dead after attention; H consumed by FFN2
    //  before next layer's QKV GEMM rewrites Q.
    //  PEW (fp32 [1024][1536], 6 MB) = Ob: produced+consumed before attention
    //  writes Ob in layer 1; unused afterwards.
    ushort_t* Hbf  = Qhi;
    float*    PEW  = Ob;

    add_pos_kernel<<<(int)(NXD / 256), 256, 0, stream>>>(x, pe, X, Xraw);

    for (int i = 0; i < N_LAYERS; i++) {
        conv_qkvw_kernel<<<1536 * 512 / 256, 256, 0, stream>>>(
            w_qs + (size_t)i * N_HEAD * D_MODEL * D_HEAD,
            w_ks + (size_t)i * N_HEAD * D_MODEL * D_HEAD,
            w_vs + (size_t)i * N_HEAD * D_MODEL * D_HEAD,
            Wqkv + (size_t)i * 1536 * 512,
            (i == 0) ? WqkvL : (ushort_t*)nullptr);
    }
    conv_bf16_kernel<<<(N_LAYERS * D_INNER * D_MODEL) / 256, 256, 0, stream>>>(
        w1, W1b, N_LAYERS * D_INNER * D_MODEL);
    conv_bf16_kernel<<<(N_LAYERS * D_MODEL * D_INNER) / 256, 256, 0, stream>>>(
        w2, W2b, N_LAYERS * D_MODEL * D_INNER);

    for (int i = 0; i < N_LAYERS; i++) {
        if (i == 0) {
            // peW = pe @ Wqkv, fp32-accurate (hi/lo), M=1024 (batch-invariant)
            gemm_hilo_kernel<<<dim3(1536 / 64, SEQ / 64), 256, 0, stream>>>(
                pe, Wqkv, WqkvL, PEW, SEQ, 1536, D_MODEL);
            // QKV = xW (plain bf16) + peW (epilogue add) -> hi/lo scatter
            gemm_kernel<0, 64, 64><<<dim3(1536 / 64, NTOK / 64), 256, 0, stream>>>(
                Xraw, Wqkv, nullptr, PEW, nullptr, nullptr,
                Qhi, Qlo, Khi, Klo, Vt, NTOK, 1536, D_MODEL);
            attention_kernel<true><<<512, 256, 0, stream>>>(
                Qhi, Qlo, Khi, Klo, Vt, Ob);
        } else {
            gemm_kernel<0, 64, 64><<<dim3(1536 / 64, NTOK / 64), 256, 0, stream>>>(
                Xbf, Wqkv + (size_t)i * 1536 * 512, nullptr, nullptr, nullptr,
                nullptr, Qhi, Qlo, Khi, Klo, Vt, NTOK, 1536, D_MODEL);
            attention_kernel<false><<<512, 256, 0, stream>>>(
                Qhi, Qlo, Khi, Klo, Vt, Ob);
        }

        add_norm_kernel<<<NTOK, 256, 0, stream>>>(
            Ob, X, ln1_a + i * D_MODEL, ln1_b + i * D_MODEL, X, Xbf);

        // FFN1: M=4096, N=1024, K=512, bias+relu -> bf16 H (aliases Qhi/Qlo)
        gemm_kernel<1, 64, 64><<<dim3(D_INNER / 64, NTOK / 64), 256, 0, stream>>>(
            Xbf, W1b + (size_t)i * D_INNER * D_MODEL, b1 + (size_t)i * D_INNER,
            nullptr, nullptr, Hbf, nullptr, nullptr, nullptr, nullptr, nullptr,
            NTOK, D_INNER, D_MODEL);

        // FFN2: M=4096, N=512, K=1024, bias -> fp32 Ob
        gemm_kernel<2, 64, 64><<<dim3(D_MODEL / 64, NTOK / 64), 256, 0, stream>>>(
            Hbf, W2b + (size_t)i * D_MODEL * D_INNER, b2 + (size_t)i * D_MODEL,
            nullptr, Ob, nullptr, nullptr, nullptr, nullptr, nullptr, nullptr,
            NTOK, D_MODEL, D_INNER);

        float* dst = (i == N_LAYERS - 1) ? out : X;
        add_norm_kernel<<<NTOK, 256, 0, stream>>>(
            Ob, X, ln2_a + i * D_MODEL, ln2_b + i * D_MODEL, dst, Xbf);
    }
}

// Round 15
// 358.954 us; speedup vs baseline: 1.1445x; 1.0280x over previous
//
#include <hip/hip_runtime.h>
#include <math.h>

#define D_MODEL 512
#define SEQ     1024
#define BATCH   4
#define N_LAYERS 2
#define N_HEAD  8
#define D_HEAD  64
#define D_INNER 1024
#define NTOK    (BATCH*SEQ)   // 4096
#define LN_EPS  1e-3f

typedef float f32x4 __attribute__((ext_vector_type(4)));
typedef short bf16x8 __attribute__((ext_vector_type(8)));
typedef unsigned short ushort_t;
typedef unsigned int uint_t;
typedef unsigned long long ull_t;

// fp32 -> bf16 round-to-nearest-even
__device__ inline ushort_t f2bf(float f) {
    uint_t u = __float_as_uint(f);
    u += 0x7FFFu + ((u >> 16) & 1u);
    return (ushort_t)(u >> 16);
}
__device__ inline float bf2f(ushort_t h) {
    return __uint_as_float((uint_t)h << 16);
}

// ---------------------------------------------------------------- fused prep
// One launch replaces: add_pos, conv_qkvw x2, conv_bf16(w1), conv_bf16(w2).
// Region-partitioned grid; branching is block-uniform except at boundaries.
//  R0 [0, E0):        X = x + pe ; Xraw = bf16(x)
//  R1 [E0, E0+2*E1):  QKV weight pack, layer l = local/E1 (lo only for l=0)
//  R2 (next EW):      w1 -> bf16
//  R3 (next EW):      w2 -> bf16
#define PREP_E0 (NTOK * D_MODEL)                  // 2,097,152
#define PREP_E1 (1536 * 512)                      // 786,432
#define PREP_EW (N_LAYERS * D_INNER * D_MODEL)    // 1,048,576
#define PREP_TOTAL (PREP_E0 + 2 * PREP_E1 + 2 * PREP_EW)

__global__ void prep_kernel(const float* __restrict__ x,
                            const float* __restrict__ pe,
                            const float* __restrict__ w_qs,
                            const float* __restrict__ w_ks,
                            const float* __restrict__ w_vs,
                            const float* __restrict__ w1,
                            const float* __restrict__ w2,
                            float* __restrict__ X,
                            ushort_t* __restrict__ Xraw,
                            ushort_t* __restrict__ Wqkv,
                            ushort_t* __restrict__ WqkvL,
                            ushort_t* __restrict__ W1b,
                            ushort_t* __restrict__ W2b) {
    int idx = blockIdx.x * 256 + threadIdx.x;
    if (idx < PREP_E0) {
        // add_pos
        int l = (idx / D_MODEL) % SEQ;
        int d = idx % D_MODEL;
        float xv = x[idx];
        X[idx] = xv + pe[l * D_MODEL + d];
        Xraw[idx] = f2bf(xv);
        return;
    }
    idx -= PREP_E0;
    if (idx < 2 * PREP_E1) {
        // QKV weight pack into Bt layout [1536][512]
        int layer = idx / PREP_E1;
        int j = idx - layer * PREP_E1;
        int n = j >> 9, k = j & 511;
        int which = n >> 9, h = (n >> 6) & 7, d = n & 63;
        size_t wofs = (size_t)layer * N_HEAD * D_MODEL * D_HEAD;
        const float* W = (which == 0) ? w_qs + wofs
                       : (which == 1) ? w_ks + wofs : w_vs + wofs;
        float v = W[((size_t)h * D_MODEL + k) * D_HEAD + d];
        ushort_t hv = f2bf(v);
        Wqkv[(size_t)layer * PREP_E1 + j] = hv;
        if (layer == 0) WqkvL[j] = f2bf(v - bf2f(hv));
        return;
    }
    idx -= 2 * PREP_E1;
    if (idx < PREP_EW) { W1b[idx] = f2bf(w1[idx]); return; }
    idx -= PREP_EW;
    W2b[idx] = f2bf(w2[idx]);
}

// ---------------------------------------------------------------- QKV scatter
// n in [0,1536): which=n>>9 (0:Q 1:K 2:V), head=(n>>6)&7, d=n&63.
// Optional pew add (layer 1): acc += peW[l][n], broadcast over batch.
// Q,K -> hi/lo bf16 [hb][seq][64]; V -> bf16 transposed [hb][dim][seq].
__device__ inline void qkv_scatter(f32x4 a, int n, int m_base,
                                   const float* __restrict__ pew,
                                   ushort_t* Qhi, ushort_t* Qlo,
                                   ushort_t* Khi, ushort_t* Klo,
                                   ushort_t* Vt) {
    int which = n >> 9, hd = n & 511;
    int head = hd >> 6, d = hd & 63;
    int hb = head * BATCH + (m_base >> 10);
    int l  = m_base & 1023;
    if (pew) {
#pragma unroll
        for (int r = 0; r < 4; r++) a[r] += pew[(size_t)(l + r) * 1536 + n];
    }
    if (which == 2) {
        ushort4 pk = make_ushort4(f2bf(a[0]), f2bf(a[1]), f2bf(a[2]), f2bf(a[3]));
        *(ushort4*)(Vt + ((size_t)hb * D_HEAD + d) * SEQ + l) = pk;
    } else {
        ushort_t* H = (which == 0) ? Qhi : Khi;
        ushort_t* L = (which == 0) ? Qlo : Klo;
#pragma unroll
        for (int r = 0; r < 4; r++) {
            float v = a[r];
            ushort_t hv = f2bf(v);
            size_t off = ((size_t)hb * SEQ + l + r) * D_HEAD + d;
            H[off] = hv;
            L[off] = f2bf(v - bf2f(hv));
        }
    }
}

// ---------------------------------------------------------------- MFMA GEMM
// C[M,N] = A[M,K] @ Bt[N,K]^T ; A,Bt bf16 row-major, acc fp32.
// Block: 256 thr = 4 waves (2x2), tile 64x64 (128-tiles regressed: grid too
// small to hide barriers — R10; launch_bounds(256,4) neutral — R12).
// MODE 0: (+pew) qkv_scatter  MODE 1: +bias, relu, bf16 out  MODE 2: +bias, fp32 out
template<int MODE, int TM, int TN>
__global__ __launch_bounds__(256, 4)
void gemm_kernel(const ushort_t* __restrict__ A, const ushort_t* __restrict__ Bt,
                 const float* __restrict__ bias, const float* __restrict__ pew,
                 float* __restrict__ outF, ushort_t* __restrict__ outB,
                 ushort_t* __restrict__ Qhi, ushort_t* __restrict__ Qlo,
                 ushort_t* __restrict__ Khi, ushort_t* __restrict__ Klo,
                 ushort_t* __restrict__ Vt,
                 int M, int N, int K) {
    constexpr int WM = TM / 2, WN = TN / 2;
    constexpr int MT = WM / 16, NT = WN / 16;
    __shared__ ushort_t As[TM][72];   // +8 pad: keeps 16B align, breaks bank alias
    __shared__ ushort_t Bs[TN][72];
    const int tid = threadIdx.x;
    const int m0 = blockIdx.y * TM, n0 = blockIdx.x * TN;
    const int w = tid >> 6, lane = tid & 63;
    const int wr = w >> 1, wc = w & 1;
    const int col = lane & 15, quad = lane >> 4;

    f32x4 acc[MT][NT] = {};

    for (int k0 = 0; k0 < K; k0 += 64) {
        __syncthreads();
#pragma unroll
        for (int p = 0; p < TM / 32; p++) {    // TM*8 chunk tasks
            int idx = p * 256 + tid;
            int row = idx >> 3, ch = (idx & 7) * 8;
            *(uint4*)(&As[row][ch]) =
                *(const uint4*)(A + (size_t)(m0 + row) * K + k0 + ch);
        }
#pragma unroll
        for (int p = 0; p < TN / 32; p++) {
            int idx = p * 256 + tid;
            int row = idx >> 3, ch = (idx & 7) * 8;
            *(uint4*)(&Bs[row][ch]) =
                *(const uint4*)(Bt + (size_t)(n0 + row) * K + k0 + ch);
        }
        __syncthreads();
#pragma unroll
        for (int ks = 0; ks < 64; ks += 32) {
            bf16x8 af[MT], bfr[NT];
#pragma unroll
            for (int t = 0; t < MT; t++)
                af[t] = *(const bf16x8*)(&As[wr * WM + t * 16 + col][ks + quad * 8]);
#pragma unroll
            for (int t = 0; t < NT; t++)
                bfr[t] = *(const bf16x8*)(&Bs[wc * WN + t * 16 + col][ks + quad * 8]);
#pragma unroll
            for (int mt = 0; mt < MT; mt++)
#pragma unroll
                for (int nt = 0; nt < NT; nt++)
                    acc[mt][nt] = __builtin_amdgcn_mfma_f32_16x16x32_bf16(
                        af[mt], bfr[nt], acc[mt][nt], 0, 0, 0);
        }
    }

#pragma unroll
    for (int mt = 0; mt < MT; mt++) {
#pragma unroll
        for (int nt = 0; nt < NT; nt++) {
            int n = n0 + wc * WN + nt * 16 + col;
            int m_base = m0 + wr * WM + mt * 16 + quad * 4;
            if (MODE == 0) {
                qkv_scatter(acc[mt][nt], n, m_base, pew, Qhi, Qlo, Khi, Klo, Vt);
            } else {
#pragma unroll
                for (int r = 0; r < 4; r++) {
                    int m = m_base + r;
                    float v = acc[mt][nt][r];
                    if (MODE == 1) {
                        float t = fmaxf(v + bias[n], 0.f);
                        outB[(size_t)m * N + n] = f2bf(t);
                    } else {
                        outF[(size_t)m * N + n] = v + bias[n];
                    }
                }
            }
        }
    }
}

// ---------------------------------------------------------------- hi/lo GEMM
// High-precision bf16 GEMM: A fp32 split in-kernel into hi+lo bf16; Bt
// pre-split (hi,lo). acc = Ah*Bh + Ah*Bl + Al*Bh (~1e-5 rel). fp32 out [M][N].
// Used for peW = pos_enc @ Wqkv (M=SEQ=1024).
__global__ __launch_bounds__(256, 4)
void gemm_hilo_kernel(const float* __restrict__ A,
                      const ushort_t* __restrict__ Bh,
                      const ushort_t* __restrict__ Bl,
                      float* __restrict__ outF, int M, int N, int K) {
    __shared__ ushort_t Ash[64][72];
    __shared__ ushort_t Asl[64][72];
    __shared__ ushort_t Bsh[64][72];
    __shared__ ushort_t Bsl[64][72];
    const int tid = threadIdx.x;
    const int m0 = blockIdx.y * 64, n0 = blockIdx.x * 64;
    const int w = tid >> 6, lane = tid & 63;
    const int wm = (w >> 1) * 32, wn = (w & 1) * 32;
    const int col = lane & 15, quad = lane >> 4;

    f32x4 acc[2][2] = {};

    for (int k0 = 0; k0 < K; k0 += 64) {
        __syncthreads();
#pragma unroll
        for (int p = 0; p < 4; p++) {
            int idx = p * 256 + tid;
            int row = idx >> 4, c4 = (idx & 15) * 4;
            float4 v = *(const float4*)(A + (size_t)(m0 + row) * K + k0 + c4);
            ushort_t h0 = f2bf(v.x), h1 = f2bf(v.y), h2 = f2bf(v.z), h3 = f2bf(v.w);
            *(ushort4*)(&Ash[row][c4]) = make_ushort4(h0, h1, h2, h3);
            *(ushort4*)(&Asl[row][c4]) = make_ushort4(
                f2bf(v.x - bf2f(h0)), f2bf(v.y - bf2f(h1)),
                f2bf(v.z - bf2f(h2)), f2bf(v.w - bf2f(h3)));
        }
#pragma unroll
        for (int p = 0; p < 2; p++) {
            int idx = p * 256 + tid;
            int row = idx >> 3, ch = (idx & 7) * 8;
            *(uint4*)(&Bsh[row][ch]) =
                *(const uint4*)(Bh + (size_t)(n0 + row) * K + k0 + ch);
            *(uint4*)(&Bsl[row][ch]) =
                *(const uint4*)(Bl + (size_t)(n0 + row) * K + k0 + ch);
        }
        __syncthreads();
#pragma unroll
        for (int ks = 0; ks < 64; ks += 32) {
            bf16x8 ah[2], al[2], bh[2], bl[2];
#pragma unroll
            for (int t = 0; t < 2; t++) {
                ah[t] = *(const bf16x8*)(&Ash[wm + t * 16 + col][ks + quad * 8]);
                al[t] = *(const bf16x8*)(&Asl[wm + t * 16 + col][ks + quad * 8]);
                bh[t] = *(const bf16x8*)(&Bsh[wn + t * 16 + col][ks + quad * 8]);
                bl[t] = *(const bf16x8*)(&Bsl[wn + t * 16 + col][ks + quad * 8]);
            }
#pragma unroll
            for (int mt = 0; mt < 2; mt++)
#pragma unroll
                for (int nt = 0; nt < 2; nt++) {
                    acc[mt][nt] = __builtin_amdgcn_mfma_f32_16x16x32_bf16(
                        ah[mt], bh[nt], acc[mt][nt], 0, 0, 0);
                    acc[mt][nt] = __builtin_amdgcn_mfma_f32_16x16x32_bf16(
                        ah[mt], bl[nt], acc[mt][nt], 0, 0, 0);
                    acc[mt][nt] = __builtin_amdgcn_mfma_f32_16x16x32_bf16(
                        al[mt], bh[nt], acc[mt][nt], 0, 0, 0);
                }
        }
    }

#pragma unroll
    for (int mt = 0; mt < 2; mt++)
#pragma unroll
        for (int nt = 0; nt < 2; nt++) {
            int n = n0 + wn + nt * 16 + col;
#pragma unroll
            for (int r = 0; r < 4; r++) {
                int m = m0 + wm + mt * 16 + quad * 4 + r;
                outF[(size_t)m * N + n] = acc[mt][nt][r];
            }
        }
}

// ---------------------------------------------------------------- attention
// MFMA flash attention — R9-proven single-buffer structure (2 barriers/tile)
// + TBAA fence before the P round-trip read. Template HILO: layer 1 needs
// fp32-accurate scores (hi/lo K and Q, 6 MFMAs); layer 2's LN'd inputs give
// score spread ~0.07 with bf16 error ~1e-4 — plain bf16 (4 MFMAs, skip Kl).
// Block = 64 Q-rows of one (b,h); XCD swizzle keeps each hb on one XCD.
template<bool HILO>
__global__ __launch_bounds__(256, 2)
void attention_kernel(const ushort_t* __restrict__ Qhi,
                      const ushort_t* __restrict__ Qlo,
                      const ushort_t* __restrict__ Khi,
                      const ushort_t* __restrict__ Klo,
                      const ushort_t* __restrict__ Vt,
                      float* __restrict__ O) {
    const int bid = blockIdx.x;          // 512
    const int j   = bid >> 3;
    const int hb  = (bid & 7) * 4 + (j >> 4);
    const int qt  = j & 15;
    const int h = hb >> 2, b = hb & 3;
    const int tid = threadIdx.x;
    const int w = tid >> 6, lane = tid & 63;
    const int col = lane & 15, quad = lane >> 4;
    const size_t kbase = (size_t)hb * SEQ * D_HEAD;
    const size_t vbase = (size_t)hb * D_HEAD * SEQ;

    __shared__ ushort_t Kh[64][72];
    __shared__ ushort_t Kl[HILO ? 64 : 1][72];
    __shared__ ushort_t Vs[64][72];     // V^T tile [dim][key]
    __shared__ ushort_t Pl[4][16][68];  // per-wave P [qrow][key], stride 68

    // Q fragments (A-layout) straight from global; lo only when HILO
    bf16x8 qh[2], ql[2];
    {
        const ushort_t* qp = Qhi + kbase + (size_t)(qt * 64 + w * 16 + col) * D_HEAD;
        qh[0] = *(const bf16x8*)(qp + quad * 8);
        qh[1] = *(const bf16x8*)(qp + 32 + quad * 8);
        if (HILO) {
            const ushort_t* lp = Qlo + kbase + (size_t)(qt * 64 + w * 16 + col) * D_HEAD;
            ql[0] = *(const bf16x8*)(lp + quad * 8);
            ql[1] = *(const bf16x8*)(lp + 32 + quad * 8);
        }
    }

    f32x4 acco[4] = {};
    float mrun[4], lrun[4];
#pragma unroll
    for (int r = 0; r < 4; r++) { mrun[r] = -1e30f; lrun[r] = 0.f; }
    const float inv_temper = 0.04419417382415922f;  // 1/sqrt(512)

    for (int t0 = 0; t0 < SEQ; t0 += 64) {
        __syncthreads();   // prev tile's reads done before restage
#pragma unroll
        for (int p = 0; p < 2; p++) {
            int idx = p * 256 + tid;          // 512 tasks: 64 rows x 8 chunks
            int row = idx >> 3, ch = (idx & 7) * 8;
            *(uint4*)(&Kh[row][ch]) =
                *(const uint4*)(Khi + kbase + (size_t)(t0 + row) * D_HEAD + ch);
            if (HILO)
                *(uint4*)(&Kl[row][ch]) =
                    *(const uint4*)(Klo + kbase + (size_t)(t0 + row) * D_HEAD + ch);
            *(uint4*)(&Vs[row][ch]) =
                *(const uint4*)(Vt + vbase + (size_t)row * SEQ + t0 + ch);
        }
        __syncthreads();

        // S = Q K^T, keys nt*16+col, rows quad*4+r
        float sc[4][4];
#pragma unroll
        for (int nt = 0; nt < 4; nt++) {
            bf16x8 bh0 = *(const bf16x8*)(&Kh[nt * 16 + col][quad * 8]);
            bf16x8 bh1 = *(const bf16x8*)(&Kh[nt * 16 + col][32 + quad * 8]);
            f32x4 s = {};
            s = __builtin_amdgcn_mfma_f32_16x16x32_bf16(qh[0], bh0, s, 0, 0, 0);
            s = __builtin_amdgcn_mfma_f32_16x16x32_bf16(qh[1], bh1, s, 0, 0, 0);
            if (HILO) {
                bf16x8 bl0 = *(const bf16x8*)(&Kl[nt * 16 + col][quad * 8]);
                bf16x8 bl1 = *(const bf16x8*)(&Kl[nt * 16 + col][32 + quad * 8]);
                s = __builtin_amdgcn_mfma_f32_16x16x32_bf16(qh[0], bl0, s, 0, 0, 0);
                s = __builtin_amdgcn_mfma_f32_16x16x32_bf16(qh[1], bl1, s, 0, 0, 0);
                s = __builtin_amdgcn_mfma_f32_16x16x32_bf16(ql[0], bh0, s, 0, 0, 0);
                s = __builtin_amdgcn_mfma_f32_16x16x32_bf16(ql[1], bh1, s, 0, 0, 0);
            }
#pragma unroll
            for (int r = 0; r < 4; r++) sc[nt][r] = s[r] * inv_temper;
        }

        // online softmax: row stats via quad shfl_xor reductions
        float tmax[4];
#pragma unroll
        for (int r = 0; r < 4; r++)
            tmax[r] = fmaxf(fmaxf(sc[0][r], sc[1][r]), fmaxf(sc[2][r], sc[3][r]));
#pragma unroll
        for (int mask = 1; mask < 16; mask <<= 1)
#pragma unroll
            for (int r = 0; r < 4; r++)
                tmax[r] = fmaxf(tmax[r], __shfl_xor(tmax[r], mask, 64));

        float alpha[4], tsum[4];
#pragma unroll
        for (int r = 0; r < 4; r++) {
            float mn = fmaxf(mrun[r], tmax[r]);
            alpha[r] = __expf(mrun[r] - mn);
            mrun[r] = mn;
            tsum[r] = 0.f;
        }
#pragma unroll
        for (int nt = 0; nt < 4; nt++)
#pragma unroll
            for (int r = 0; r < 4; r++) {
                float pv = __expf(sc[nt][r] - mrun[r]);
                tsum[r] += pv;
                Pl[w][quad * 4 + r][nt * 16 + col] = f2bf(pv);
            }
#pragma unroll
        for (int mask = 1; mask < 16; mask <<= 1)
#pragma unroll
            for (int r = 0; r < 4; r++)
                tsum[r] += __shfl_xor(tsum[r], mask, 64);
#pragma unroll
        for (int r = 0; r < 4; r++)
            lrun[r] = lrun[r] * alpha[r] + tsum[r];
#pragma unroll
        for (int nt = 0; nt < 4; nt++)
#pragma unroll
            for (int r = 0; r < 4; r++)
                acco[nt][r] *= alpha[r];

        // Order the Pl stores before the type-punned reads below (wave-local
        // visibility; also a compiler fence against TBAA reordering).
        __threadfence_block();

        // P (A-layout) and PV
        union { ulong2 u; bf16x8 v; } a0, a1;
        a0.u.x = *(const ull_t*)(&Pl[w][col][quad * 8]);
        a0.u.y = *(const ull_t*)(&Pl[w][col][quad * 8 + 4]);
        a1.u.x = *(const ull_t*)(&Pl[w][col][32 + quad * 8]);
        a1.u.y = *(const ull_t*)(&Pl[w][col][32 + quad * 8 + 4]);
#pragma unroll
        for (int nt = 0; nt < 4; nt++) {
            bf16x8 bv0 = *(const bf16x8*)(&Vs[nt * 16 + col][quad * 8]);
            bf16x8 bv1 = *(const bf16x8*)(&Vs[nt * 16 + col][32 + quad * 8]);
            acco[nt] = __builtin_amdgcn_mfma_f32_16x16x32_bf16(a0.v, bv0, acco[nt], 0, 0, 0);
            acco[nt] = __builtin_amdgcn_mfma_f32_16x16x32_bf16(a1.v, bv1, acco[nt], 0, 0, 0);
        }
    }

    // epilogue: O[b][row][h*64 + dim], dim = nt*16+col, row = qt*64+w*16+quad*4+r
#pragma unroll
    for (int nt = 0; nt < 4; nt++) {
#pragma unroll
        for (int r = 0; r < 4; r++) {
            int row = qt * 64 + w * 16 + quad * 4 + r;
            O[((size_t)b * SEQ + row) * D_MODEL + h * D_HEAD + nt * 16 + col]
                = acco[nt][r] / lrun[r];
        }
    }
}

// ---------------------------------------------------------------- add + LN
__device__ inline float block_sum_256(float v, float* tmp) {
#pragma unroll
    for (int off = 32; off > 0; off >>= 1) v += __shfl_down(v, off, 64);
    if ((threadIdx.x & 63) == 0) tmp[threadIdx.x >> 6] = v;
    __syncthreads();
    return tmp[0] + tmp[1] + tmp[2] + tmp[3];
}

// Writes fp32 Out AND bf16 OutBf. Safe for Out==R (in-place).
__global__ void add_norm_kernel(const float* __restrict__ A,
                                const float* __restrict__ R,
                                const float* __restrict__ ga,
                                const float* __restrict__ gb,
                                float* __restrict__ Out,
                                ushort_t* __restrict__ OutBf) {
    int tok = blockIdx.x, tid = threadIdx.x;
    __shared__ float t1[4], t2[4];
    size_t base = (size_t)tok * D_MODEL;
    float z0 = A[base + tid]       + R[base + tid];
    float z1 = A[base + tid + 256] + R[base + tid + 256];
    float s = block_sum_256(z0 + z1, t1);
    float mu = s * (1.f / (float)D_MODEL);
    float d0 = z0 - mu, d1 = z1 - mu;
    float ss = block_sum_256(d0 * d0 + d1 * d1, t2);
    float sigma = sqrtf(ss * (1.f / (float)(D_MODEL - 1)));
    float inv = 1.f / (sigma + LN_EPS);
    float r0 = d0 * inv * ga[tid]       + gb[tid];
    float r1 = d1 * inv * ga[tid + 256] + gb[tid + 256];
    Out[base + tid]         = r0;
    Out[base + tid + 256]   = r1;
    OutBf[base + tid]       = f2bf(r0);
    OutBf[base + tid + 256] = f2bf(r1);
}

// ---------------------------------------------------------------- launch
extern "C" void kernel_launch(void* const* d_in, const int* in_sizes, int n_in,
                              void* d_out, int out_size, void* d_ws, size_t ws_size,
                              hipStream_t stream) {
    const float* x     = (const float*)d_in[0];
    const float* pe    = (const float*)d_in[1];
    const float* w_qs  = (const float*)d_in[2];
    const float* w_ks  = (const float*)d_in[3];
    const float* w_vs  = (const float*)d_in[4];
    const float* ln1_a = (const float*)d_in[5];
    const float* ln1_b = (const float*)d_in[6];
    const float* w1    = (const float*)d_in[7];
    const float* b1    = (const float*)d_in[8];
    const float* w2    = (const float*)d_in[9];
    const float* b2    = (const float*)d_in[10];
    const float* ln2_a = (const float*)d_in[11];
    const float* ln2_b = (const float*)d_in[12];
    float* out = (float*)d_out;

    const size_t NXD = (size_t)NTOK * D_MODEL;       // 2M elements
    char* p = (char*)d_ws;
    float*    X    = (float*)p;     p += NXD * 4;                 // 8 MB
    float*    Ob   = (float*)p;     p += NXD * 4;                 // 8 MB
    ushort_t* Xbf  = (ushort_t*)p;  p += NXD * 2;                 // 4 MB
    ushort_t* Xraw = (ushort_t*)p;  p += NXD * 2;                 // 4 MB  bf16(x)
    ushort_t* Qhi  = (ushort_t*)p;  p += NXD * 2;                 // 4 MB
    ushort_t* Qlo  = (ushort_t*)p;  p += NXD * 2;                 // 4 MB
    ushort_t* Khi  = (ushort_t*)p;  p += NXD * 2;                 // 4 MB
    ushort_t* Klo  = (ushort_t*)p;  p += NXD * 2;                 // 4 MB
    ushort_t* Vt   = (ushort_t*)p;  p += NXD * 2;                 // 4 MB
    ushort_t* Wqkv = (ushort_t*)p;  p += (size_t)N_LAYERS * 1536 * 512 * 2;  // 3 MB (hi)
    ushort_t* WqkvL= (ushort_t*)p;  p += (size_t)1536 * 512 * 2;  // 1.5 MB (lo, layer 0)
    ushort_t* W1b  = (ushort_t*)p;  p += (size_t)N_LAYERS * D_INNER * D_MODEL * 2;  // 2 MB
    ushort_t* W2b  = (ushort_t*)p;  /* 2 MB */
    // Aliases (stream-ordered safe):
    //  H (bf16, 8 MB) = Qhi+Qlo: Q dead after attention; H consumed by FFN2
    //  before next layer's QKV GEMM rewrites Q.
    //  PEW (fp32 [1024][1536], 6 MB) = Ob: produced+consumed before attention
    //  writes Ob in layer 1; unused afterwards.
    ushort_t* Hbf  = Qhi;
    float*    PEW  = Ob;

    // fused setup: add_pos + QKV weight pack (x2) + w1/w2 bf16 conversion
    prep_kernel<<<(PREP_TOTAL + 255) / 256, 256, 0, stream>>>(
        x, pe, w_qs, w_ks, w_vs, w1, w2, X, Xraw, Wqkv, WqkvL, W1b, W2b);

    for (int i = 0; i < N_LAYERS; i++) {
        if (i == 0) {
            // peW = pe @ Wqkv, fp32-accurate (hi/lo), M=1024 (batch-invariant)
            gemm_hilo_kernel<<<dim3(1536 / 64, SEQ / 64), 256, 0, stream>>>(
                pe, Wqkv, WqkvL, PEW, SEQ, 1536, D_MODEL);
            // QKV = xW (plain bf16) + peW (epilogue add) -> hi/lo scatter
            gemm_kernel<0, 64, 64><<<dim3(1536 / 64, NTOK / 64), 256, 0, stream>>>(
                Xraw, Wqkv, nullptr, PEW, nullptr, nullptr,
                Qhi, Qlo, Khi, Klo, Vt, NTOK, 1536, D_MODEL);
            attention_kernel<true><<<512, 256, 0, stream>>>(
                Qhi, Qlo, Khi, Klo, Vt, Ob);
        } else {
            gemm_kernel<0, 64, 64><<<dim3(1536 / 64, NTOK / 64), 256, 0, stream>>>(
                Xbf, Wqkv + (size_t)i * 1536 * 512, nullptr, nullptr, nullptr,
                nullptr, Qhi, Qlo, Khi, Klo, Vt, NTOK, 1536, D_MODEL);
            attention_kernel<false><<<512, 256, 0, stream>>>(
                Qhi, Qlo, Khi, Klo, Vt, Ob);
        }

        add_norm_kernel<<<NTOK, 256, 0, stream>>>(
            Ob, X, ln1_a + i * D_MODEL, ln1_b + i * D_MODEL, X, Xbf);

        // FFN1: M=4096, N=1024, K=512, bias+relu -> bf16 H (aliases Qhi/Qlo)
        gemm_kernel<1, 64, 64><<<dim3(D_INNER / 64, NTOK / 64), 256, 0, stream>>>(
            Xbf, W1b + (size_t)i * D_INNER * D_MODEL, b1 + (size_t)i * D_INNER,
            nullptr, nullptr, Hbf, nullptr, nullptr, nullptr, nullptr, nullptr,
            NTOK, D_INNER, D_MODEL);

        // FFN2: M=4096, N=512, K=1024, bias -> fp32 Ob
        gemm_kernel<2, 64, 64><<<dim3(D_MODEL / 64, NTOK / 64), 256, 0, stream>>>(
            Hbf, W2b + (size_t)i * D_MODEL * D_INNER, b2 + (size_t)i * D_MODEL,
            nullptr, Ob, nullptr, nullptr, nullptr, nullptr, nullptr, nullptr,
            NTOK, D_MODEL, D_INNER);

        float* dst = (i == N_LAYERS - 1) ? out : X;
        add_norm_kernel<<<NTOK, 256, 0, stream>>>(
            Ob, X, ln2_a + i * D_MODEL, ln2_b + i * D_MODEL, dst, Xbf);
    }
}

// Round 16
// 337.220 us; speedup vs baseline: 1.2182x; 1.0645x over previous
//
#include <hip/hip_runtime.h>
#include <math.h>

#define D_MODEL 512
#define SEQ     1024
#define BATCH   4
#define N_LAYERS 2
#define N_HEAD  8
#define D_HEAD  64
#define D_INNER 1024
#define NTOK    (BATCH*SEQ)   // 4096
#define LN_EPS  1e-3f

typedef float f32x4 __attribute__((ext_vector_type(4)));
typedef short bf16x8 __attribute__((ext_vector_type(8)));
typedef unsigned short ushort_t;
typedef unsigned int uint_t;
typedef unsigned long long ull_t;

// fp32 -> bf16 round-to-nearest-even
__device__ inline ushort_t f2bf(float f) {
    uint_t u = __float_as_uint(f);
    u += 0x7FFFu + ((u >> 16) & 1u);
    return (ushort_t)(u >> 16);
}
__device__ inline float bf2f(ushort_t h) {
    return __uint_as_float((uint_t)h << 16);
}

// ---------------------------------------------------------------- fused prep
// One launch replaces: add_pos, conv_qkvw x2, conv_bf16(w1), conv_bf16(w2).
#define PREP_E0 (NTOK * D_MODEL)                  // 2,097,152
#define PREP_E1 (1536 * 512)                      // 786,432
#define PREP_EW (N_LAYERS * D_INNER * D_MODEL)    // 1,048,576
#define PREP_TOTAL (PREP_E0 + 2 * PREP_E1 + 2 * PREP_EW)

__global__ void prep_kernel(const float* __restrict__ x,
                            const float* __restrict__ pe,
                            const float* __restrict__ w_qs,
                            const float* __restrict__ w_ks,
                            const float* __restrict__ w_vs,
                            const float* __restrict__ w1,
                            const float* __restrict__ w2,
                            float* __restrict__ X,
                            ushort_t* __restrict__ Xraw,
                            ushort_t* __restrict__ Wqkv,
                            ushort_t* __restrict__ WqkvL,
                            ushort_t* __restrict__ W1b,
                            ushort_t* __restrict__ W2b) {
    int idx = blockIdx.x * 256 + threadIdx.x;
    if (idx < PREP_E0) {
        int l = (idx / D_MODEL) % SEQ;
        int d = idx % D_MODEL;
        float xv = x[idx];
        X[idx] = xv + pe[l * D_MODEL + d];
        Xraw[idx] = f2bf(xv);
        return;
    }
    idx -= PREP_E0;
    if (idx < 2 * PREP_E1) {
        int layer = idx / PREP_E1;
        int j = idx - layer * PREP_E1;
        int n = j >> 9, k = j & 511;
        int which = n >> 9, h = (n >> 6) & 7, d = n & 63;
        size_t wofs = (size_t)layer * N_HEAD * D_MODEL * D_HEAD;
        const float* W = (which == 0) ? w_qs + wofs
                       : (which == 1) ? w_ks + wofs : w_vs + wofs;
        float v = W[((size_t)h * D_MODEL + k) * D_HEAD + d];
        ushort_t hv = f2bf(v);
        Wqkv[(size_t)layer * PREP_E1 + j] = hv;
        if (layer == 0) WqkvL[j] = f2bf(v - bf2f(hv));
        return;
    }
    idx -= 2 * PREP_E1;
    if (idx < PREP_EW) { W1b[idx] = f2bf(w1[idx]); return; }
    idx -= PREP_EW;
    W2b[idx] = f2bf(w2[idx]);
}

// ---------------------------------------------------------------- QKV scatter
__device__ inline void qkv_scatter(f32x4 a, int n, int m_base,
                                   const float* __restrict__ pew,
                                   ushort_t* Qhi, ushort_t* Qlo,
                                   ushort_t* Khi, ushort_t* Klo,
                                   ushort_t* Vt) {
    int which = n >> 9, hd = n & 511;
    int head = hd >> 6, d = hd & 63;
    int hb = head * BATCH + (m_base >> 10);
    int l  = m_base & 1023;
    if (pew) {
#pragma unroll
        for (int r = 0; r < 4; r++) a[r] += pew[(size_t)(l + r) * 1536 + n];
    }
    if (which == 2) {
        ushort4 pk = make_ushort4(f2bf(a[0]), f2bf(a[1]), f2bf(a[2]), f2bf(a[3]));
        *(ushort4*)(Vt + ((size_t)hb * D_HEAD + d) * SEQ + l) = pk;
    } else {
        ushort_t* H = (which == 0) ? Qhi : Khi;
        ushort_t* L = (which == 0) ? Qlo : Klo;
#pragma unroll
        for (int r = 0; r < 4; r++) {
            float v = a[r];
            ushort_t hv = f2bf(v);
            size_t off = ((size_t)hb * SEQ + l + r) * D_HEAD + d;
            H[off] = hv;
            L[off] = f2bf(v - bf2f(hv));
        }
    }
}

// ---------------------------------------------------------------- MFMA GEMM
// 64x64 proven config (128-tiles ✗ R10; launch_bounds(256,4) neutral R12).
template<int MODE, int TM, int TN>
__global__ __launch_bounds__(256, 4)
void gemm_kernel(const ushort_t* __restrict__ A, const ushort_t* __restrict__ Bt,
                 const float* __restrict__ bias, const float* __restrict__ pew,
                 float* __restrict__ outF, ushort_t* __restrict__ outB,
                 ushort_t* __restrict__ Qhi, ushort_t* __restrict__ Qlo,
                 ushort_t* __restrict__ Khi, ushort_t* __restrict__ Klo,
                 ushort_t* __restrict__ Vt,
                 int M, int N, int K) {
    constexpr int WM = TM / 2, WN = TN / 2;
    constexpr int MT = WM / 16, NT = WN / 16;
    __shared__ ushort_t As[TM][72];
    __shared__ ushort_t Bs[TN][72];
    const int tid = threadIdx.x;
    const int m0 = blockIdx.y * TM, n0 = blockIdx.x * TN;
    const int w = tid >> 6, lane = tid & 63;
    const int wr = w >> 1, wc = w & 1;
    const int col = lane & 15, quad = lane >> 4;

    f32x4 acc[MT][NT] = {};

    for (int k0 = 0; k0 < K; k0 += 64) {
        __syncthreads();
#pragma unroll
        for (int p = 0; p < TM / 32; p++) {
            int idx = p * 256 + tid;
            int row = idx >> 3, ch = (idx & 7) * 8;
            *(uint4*)(&As[row][ch]) =
                *(const uint4*)(A + (size_t)(m0 + row) * K + k0 + ch);
        }
#pragma unroll
        for (int p = 0; p < TN / 32; p++) {
            int idx = p * 256 + tid;
            int row = idx >> 3, ch = (idx & 7) * 8;
            *(uint4*)(&Bs[row][ch]) =
                *(const uint4*)(Bt + (size_t)(n0 + row) * K + k0 + ch);
        }
        __syncthreads();
#pragma unroll
        for (int ks = 0; ks < 64; ks += 32) {
            bf16x8 af[MT], bfr[NT];
#pragma unroll
            for (int t = 0; t < MT; t++)
                af[t] = *(const bf16x8*)(&As[wr * WM + t * 16 + col][ks + quad * 8]);
#pragma unroll
            for (int t = 0; t < NT; t++)
                bfr[t] = *(const bf16x8*)(&Bs[wc * WN + t * 16 + col][ks + quad * 8]);
#pragma unroll
            for (int mt = 0; mt < MT; mt++)
#pragma unroll
                for (int nt = 0; nt < NT; nt++)
                    acc[mt][nt] = __builtin_amdgcn_mfma_f32_16x16x32_bf16(
                        af[mt], bfr[nt], acc[mt][nt], 0, 0, 0);
        }
    }

#pragma unroll
    for (int mt = 0; mt < MT; mt++) {
#pragma unroll
        for (int nt = 0; nt < NT; nt++) {
            int n = n0 + wc * WN + nt * 16 + col;
            int m_base = m0 + wr * WM + mt * 16 + quad * 4;
            if (MODE == 0) {
                qkv_scatter(acc[mt][nt], n, m_base, pew, Qhi, Qlo, Khi, Klo, Vt);
            } else {
#pragma unroll
                for (int r = 0; r < 4; r++) {
                    int m = m_base + r;
                    float v = acc[mt][nt][r];
                    if (MODE == 1) {
                        float t = fmaxf(v + bias[n], 0.f);
                        outB[(size_t)m * N + n] = f2bf(t);
                    } else {
                        outF[(size_t)m * N + n] = v + bias[n];
                    }
                }
            }
        }
    }
}

// ---------------------------------------------------------------- hi/lo GEMM
// Used for peW = pos_enc @ Wqkv (M=SEQ=1024). fp32 out [M][N].
__global__ __launch_bounds__(256, 4)
void gemm_hilo_kernel(const float* __restrict__ A,
                      const ushort_t* __restrict__ Bh,
                      const ushort_t* __restrict__ Bl,
                      float* __restrict__ outF, int M, int N, int K) {
    __shared__ ushort_t Ash[64][72];
    __shared__ ushort_t Asl[64][72];
    __shared__ ushort_t Bsh[64][72];
    __shared__ ushort_t Bsl[64][72];
    const int tid = threadIdx.x;
    const int m0 = blockIdx.y * 64, n0 = blockIdx.x * 64;
    const int w = tid >> 6, lane = tid & 63;
    const int wm = (w >> 1) * 32, wn = (w & 1) * 32;
    const int col = lane & 15, quad = lane >> 4;

    f32x4 acc[2][2] = {};

    for (int k0 = 0; k0 < K; k0 += 64) {
        __syncthreads();
#pragma unroll
        for (int p = 0; p < 4; p++) {
            int idx = p * 256 + tid;
            int row = idx >> 4, c4 = (idx & 15) * 4;
            float4 v = *(const float4*)(A + (size_t)(m0 + row) * K + k0 + c4);
            ushort_t h0 = f2bf(v.x), h1 = f2bf(v.y), h2 = f2bf(v.z), h3 = f2bf(v.w);
            *(ushort4*)(&Ash[row][c4]) = make_ushort4(h0, h1, h2, h3);
            *(ushort4*)(&Asl[row][c4]) = make_ushort4(
                f2bf(v.x - bf2f(h0)), f2bf(v.y - bf2f(h1)),
                f2bf(v.z - bf2f(h2)), f2bf(v.w - bf2f(h3)));
        }
#pragma unroll
        for (int p = 0; p < 2; p++) {
            int idx = p * 256 + tid;
            int row = idx >> 3, ch = (idx & 7) * 8;
            *(uint4*)(&Bsh[row][ch]) =
                *(const uint4*)(Bh + (size_t)(n0 + row) * K + k0 + ch);
            *(uint4*)(&Bsl[row][ch]) =
                *(const uint4*)(Bl + (size_t)(n0 + row) * K + k0 + ch);
        }
        __syncthreads();
#pragma unroll
        for (int ks = 0; ks < 64; ks += 32) {
            bf16x8 ah[2], al[2], bh[2], bl[2];
#pragma unroll
            for (int t = 0; t < 2; t++) {
                ah[t] = *(const bf16x8*)(&Ash[wm + t * 16 + col][ks + quad * 8]);
                al[t] = *(const bf16x8*)(&Asl[wm + t * 16 + col][ks + quad * 8]);
                bh[t] = *(const bf16x8*)(&Bsh[wn + t * 16 + col][ks + quad * 8]);
                bl[t] = *(const bf16x8*)(&Bsl[wn + t * 16 + col][ks + quad * 8]);
            }
#pragma unroll
            for (int mt = 0; mt < 2; mt++)
#pragma unroll
                for (int nt = 0; nt < 2; nt++) {
                    acc[mt][nt] = __builtin_amdgcn_mfma_f32_16x16x32_bf16(
                        ah[mt], bh[nt], acc[mt][nt], 0, 0, 0);
                    acc[mt][nt] = __builtin_amdgcn_mfma_f32_16x16x32_bf16(
                        ah[mt], bl[nt], acc[mt][nt], 0, 0, 0);
                    acc[mt][nt] = __builtin_amdgcn_mfma_f32_16x16x32_bf16(
                        al[mt], bh[nt], acc[mt][nt], 0, 0, 0);
                }
        }
    }

#pragma unroll
    for (int mt = 0; mt < 2; mt++)
#pragma unroll
        for (int nt = 0; nt < 2; nt++) {
            int n = n0 + wn + nt * 16 + col;
#pragma unroll
            for (int r = 0; r < 4; r++) {
                int m = m0 + wm + mt * 16 + quad * 4 + r;
                outF[(size_t)m * N + n] = acc[mt][nt][r];
            }
        }
}

// ---------------------------------------------------------------- attention
// MFMA flash attention — single-LDS-buffer, TK=128: two 64-key subtiles per
// barrier pair (halves barrier count vs R13; total staged bytes unchanged).
// TBAA fence before the P round-trip read. HILO: layer 1 hi/lo scores.
// LDS: HILO 62KB (2 blocks/CU), plain 44KB. Block = 64 Q-rows of one (b,h).
template<bool HILO>
__global__ __launch_bounds__(256, 2)
void attention_kernel(const ushort_t* __restrict__ Qhi,
                      const ushort_t* __restrict__ Qlo,
                      const ushort_t* __restrict__ Khi,
                      const ushort_t* __restrict__ Klo,
                      const ushort_t* __restrict__ Vt,
                      float* __restrict__ O) {
    const int bid = blockIdx.x;          // 512
    const int j   = bid >> 3;
    const int hb  = (bid & 7) * 4 + (j >> 4);
    const int qt  = j & 15;
    const int h = hb >> 2, b = hb & 3;
    const int tid = threadIdx.x;
    const int w = tid >> 6, lane = tid & 63;
    const int col = lane & 15, quad = lane >> 4;
    const size_t kbase = (size_t)hb * SEQ * D_HEAD;
    const size_t vbase = (size_t)hb * D_HEAD * SEQ;

    __shared__ ushort_t Kh[128][72];             // 18 KB (keys x dims)
    __shared__ ushort_t Kl[HILO ? 128 : 1][72];  // 18 KB when HILO
    __shared__ ushort_t Vs[64][136];             // 17 KB (dims x 128 keys)
    __shared__ ushort_t Pl[4][16][68];           // per-wave P, 8.5 KB

    // Q fragments (A-layout) straight from global; lo only when HILO
    bf16x8 qh[2], ql[2];
    {
        const ushort_t* qp = Qhi + kbase + (size_t)(qt * 64 + w * 16 + col) * D_HEAD;
        qh[0] = *(const bf16x8*)(qp + quad * 8);
        qh[1] = *(const bf16x8*)(qp + 32 + quad * 8);
        if (HILO) {
            const ushort_t* lp = Qlo + kbase + (size_t)(qt * 64 + w * 16 + col) * D_HEAD;
            ql[0] = *(const bf16x8*)(lp + quad * 8);
            ql[1] = *(const bf16x8*)(lp + 32 + quad * 8);
        }
    }

    f32x4 acco[4] = {};
    float mrun[4], lrun[4];
#pragma unroll
    for (int r = 0; r < 4; r++) { mrun[r] = -1e30f; lrun[r] = 0.f; }
    const float inv_temper = 0.04419417382415922f;  // 1/sqrt(512)

    for (int t0 = 0; t0 < SEQ; t0 += 128) {
        __syncthreads();   // prev iteration's reads done before restage
        // K hi/lo: 128 keys x 64 dims = 1024 uint4 tasks (4/thread)
#pragma unroll
        for (int p = 0; p < 4; p++) {
            int idx = p * 256 + tid;
            int row = idx >> 3, ch = (idx & 7) * 8;
            *(uint4*)(&Kh[row][ch]) =
                *(const uint4*)(Khi + kbase + (size_t)(t0 + row) * D_HEAD + ch);
            if (HILO)
                *(uint4*)(&Kl[row][ch]) =
                    *(const uint4*)(Klo + kbase + (size_t)(t0 + row) * D_HEAD + ch);
        }
        // V^T: 64 dims x 128 keys = 1024 uint4 tasks (4/thread)
#pragma unroll
        for (int p = 0; p < 4; p++) {
            int idx = p * 256 + tid;
            int row = idx >> 4, ch = (idx & 15) * 8;
            *(uint4*)(&Vs[row][ch]) =
                *(const uint4*)(Vt + vbase + (size_t)row * SEQ + t0 + ch);
        }
        __syncthreads();

#pragma unroll
        for (int st = 0; st < 2; st++) {
            const int ko = st * 64;   // subtile key offset within LDS

            // S = Q K^T, keys ko+nt*16+col, rows quad*4+r
            float sc[4][4];
#pragma unroll
            for (int nt = 0; nt < 4; nt++) {
                bf16x8 bh0 = *(const bf16x8*)(&Kh[ko + nt * 16 + col][quad * 8]);
                bf16x8 bh1 = *(const bf16x8*)(&Kh[ko + nt * 16 + col][32 + quad * 8]);
                f32x4 s = {};
                s = __builtin_amdgcn_mfma_f32_16x16x32_bf16(qh[0], bh0, s, 0, 0, 0);
                s = __builtin_amdgcn_mfma_f32_16x16x32_bf16(qh[1], bh1, s, 0, 0, 0);
                if (HILO) {
                    bf16x8 bl0 = *(const bf16x8*)(&Kl[ko + nt * 16 + col][quad * 8]);
                    bf16x8 bl1 = *(const bf16x8*)(&Kl[ko + nt * 16 + col][32 + quad * 8]);
                    s = __builtin_amdgcn_mfma_f32_16x16x32_bf16(qh[0], bl0, s, 0, 0, 0);
                    s = __builtin_amdgcn_mfma_f32_16x16x32_bf16(qh[1], bl1, s, 0, 0, 0);
                    s = __builtin_amdgcn_mfma_f32_16x16x32_bf16(ql[0], bh0, s, 0, 0, 0);
                    s = __builtin_amdgcn_mfma_f32_16x16x32_bf16(ql[1], bh1, s, 0, 0, 0);
                }
#pragma unroll
                for (int r = 0; r < 4; r++) sc[nt][r] = s[r] * inv_temper;
            }

            // online softmax: row stats via quad shfl_xor reductions
            float tmax[4];
#pragma unroll
            for (int r = 0; r < 4; r++)
                tmax[r] = fmaxf(fmaxf(sc[0][r], sc[1][r]), fmaxf(sc[2][r], sc[3][r]));
#pragma unroll
            for (int mask = 1; mask < 16; mask <<= 1)
#pragma unroll
                for (int r = 0; r < 4; r++)
                    tmax[r] = fmaxf(tmax[r], __shfl_xor(tmax[r], mask, 64));

            float alpha[4], tsum[4];
#pragma unroll
            for (int r = 0; r < 4; r++) {
                float mn = fmaxf(mrun[r], tmax[r]);
                alpha[r] = __expf(mrun[r] - mn);
                mrun[r] = mn;
                tsum[r] = 0.f;
            }
#pragma unroll
            for (int nt = 0; nt < 4; nt++)
#pragma unroll
                for (int r = 0; r < 4; r++) {
                    float pv = __expf(sc[nt][r] - mrun[r]);
                    tsum[r] += pv;
                    Pl[w][quad * 4 + r][nt * 16 + col] = f2bf(pv);
                }
#pragma unroll
            for (int mask = 1; mask < 16; mask <<= 1)
#pragma unroll
                for (int r = 0; r < 4; r++)
                    tsum[r] += __shfl_xor(tsum[r], mask, 64);
#pragma unroll
            for (int r = 0; r < 4; r++)
                lrun[r] = lrun[r] * alpha[r] + tsum[r];
#pragma unroll
            for (int nt = 0; nt < 4; nt++)
#pragma unroll
                for (int r = 0; r < 4; r++)
                    acco[nt][r] *= alpha[r];

            // Order the Pl stores before the type-punned reads below.
            __threadfence_block();

            // P (A-layout) and PV
            union { ulong2 u; bf16x8 v; } a0, a1;
            a0.u.x = *(const ull_t*)(&Pl[w][col][quad * 8]);
            a0.u.y = *(const ull_t*)(&Pl[w][col][quad * 8 + 4]);
            a1.u.x = *(const ull_t*)(&Pl[w][col][32 + quad * 8]);
            a1.u.y = *(const ull_t*)(&Pl[w][col][32 + quad * 8 + 4]);
#pragma unroll
            for (int nt = 0; nt < 4; nt++) {
                bf16x8 bv0 = *(const bf16x8*)(&Vs[nt * 16 + col][ko + quad * 8]);
                bf16x8 bv1 = *(const bf16x8*)(&Vs[nt * 16 + col][ko + 32 + quad * 8]);
                acco[nt] = __builtin_amdgcn_mfma_f32_16x16x32_bf16(a0.v, bv0, acco[nt], 0, 0, 0);
                acco[nt] = __builtin_amdgcn_mfma_f32_16x16x32_bf16(a1.v, bv1, acco[nt], 0, 0, 0);
            }
        }
    }

    // epilogue: O[b][row][h*64 + dim], dim = nt*16+col, row = qt*64+w*16+quad*4+r
#pragma unroll
    for (int nt = 0; nt < 4; nt++) {
#pragma unroll
        for (int r = 0; r < 4; r++) {
            int row = qt * 64 + w * 16 + quad * 4 + r;
            O[((size_t)b * SEQ + row) * D_MODEL + h * D_HEAD + nt * 16 + col]
                = acco[nt][r] / lrun[r];
        }
    }
}

// ---------------------------------------------------------------- add + LN
__device__ inline float block_sum_256(float v, float* tmp) {
#pragma unroll
    for (int off = 32; off > 0; off >>= 1) v += __shfl_down(v, off, 64);
    if ((threadIdx.x & 63) == 0) tmp[threadIdx.x >> 6] = v;
    __syncthreads();
    return tmp[0] + tmp[1] + tmp[2] + tmp[3];
}

// Writes fp32 Out AND bf16 OutBf. Safe for Out==R (in-place).
__global__ void add_norm_kernel(const float* __restrict__ A,
                                const float* __restrict__ R,
                                const float* __restrict__ ga,
                                const float* __restrict__ gb,
                                float* __restrict__ Out,
                                ushort_t* __restrict__ OutBf) {
    int tok = blockIdx.x, tid = threadIdx.x;
    __shared__ float t1[4], t2[4];
    size_t base = (size_t)tok * D_MODEL;
    float z0 = A[base + tid]       + R[base + tid];
    float z1 = A[base + tid + 256] + R[base + tid + 256];
    float s = block_sum_256(z0 + z1, t1);
    float mu = s * (1.f / (float)D_MODEL);
    float d0 = z0 - mu, d1 = z1 - mu;
    float ss = block_sum_256(d0 * d0 + d1 * d1, t2);
    float sigma = sqrtf(ss * (1.f / (float)(D_MODEL - 1)));
    float inv = 1.f / (sigma + LN_EPS);
    float r0 = d0 * inv * ga[tid]       + gb[tid];
    float r1 = d1 * inv * ga[tid + 256] + gb[tid + 256];
    Out[base + tid]         = r0;
    Out[base + tid + 256]   = r1;
    OutBf[base + tid]       = f2bf(r0);
    OutBf[base + tid + 256] = f2bf(r1);
}

// ---------------------------------------------------------------- launch
extern "C" void kernel_launch(void* const* d_in, const int* in_sizes, int n_in,
                              void* d_out, int out_size, void* d_ws, size_t ws_size,
                              hipStream_t stream) {
    const float* x     = (const float*)d_in[0];
    const float* pe    = (const float*)d_in[1];
    const float* w_qs  = (const float*)d_in[2];
    const float* w_ks  = (const float*)d_in[3];
    const float* w_vs  = (const float*)d_in[4];
    const float* ln1_a = (const float*)d_in[5];
    const float* ln1_b = (const float*)d_in[6];
    const float* w1    = (const float*)d_in[7];
    const float* b1    = (const float*)d_in[8];
    const float* w2    = (const float*)d_in[9];
    const float* b2    = (const float*)d_in[10];
    const float* ln2_a = (const float*)d_in[11];
    const float* ln2_b = (const float*)d_in[12];
    float* out = (float*)d_out;

    const size_t NXD = (size_t)NTOK * D_MODEL;       // 2M elements
    char* p = (char*)d_ws;
    float*    X    = (float*)p;     p += NXD * 4;                 // 8 MB
    float*    Ob   = (float*)p;     p += NXD * 4;                 // 8 MB
    ushort_t* Xbf  = (ushort_t*)p;  p += NXD * 2;                 // 4 MB
    ushort_t* Xraw = (ushort_t*)p;  p += NXD * 2;                 // 4 MB  bf16(x)
    ushort_t* Qhi  = (ushort_t*)p;  p += NXD * 2;                 // 4 MB
    ushort_t* Qlo  = (ushort_t*)p;  p += NXD * 2;                 // 4 MB
    ushort_t* Khi  = (ushort_t*)p;  p += NXD * 2;                 // 4 MB
    ushort_t* Klo  = (ushort_t*)p;  p += NXD * 2;                 // 4 MB
    ushort_t* Vt   = (ushort_t*)p;  p += NXD * 2;                 // 4 MB
    ushort_t* Wqkv = (ushort_t*)p;  p += (size_t)N_LAYERS * 1536 * 512 * 2;  // 3 MB (hi)
    ushort_t* WqkvL= (ushort_t*)p;  p += (size_t)1536 * 512 * 2;  // 1.5 MB (lo, layer 0)
    ushort_t* W1b  = (ushort_t*)p;  p += (size_t)N_LAYERS * D_INNER * D_MODEL * 2;  // 2 MB
    ushort_t* W2b  = (ushort_t*)p;  /* 2 MB */
    // Aliases (stream-ordered safe): H = Qhi/Qlo (dead after attention);
    // PEW = Ob (produced+consumed before attention writes Ob in layer 1).
    ushort_t* Hbf  = Qhi;
    float*    PEW  = Ob;

    // fused setup: add_pos + QKV weight pack (x2) + w1/w2 bf16 conversion
    prep_kernel<<<(PREP_TOTAL + 255) / 256, 256, 0, stream>>>(
        x, pe, w_qs, w_ks, w_vs, w1, w2, X, Xraw, Wqkv, WqkvL, W1b, W2b);

    for (int i = 0; i < N_LAYERS; i++) {
        if (i == 0) {
            // peW = pe @ Wqkv, fp32-accurate (hi/lo), M=1024 (batch-invariant)
            gemm_hilo_kernel<<<dim3(1536 / 64, SEQ / 64), 256, 0, stream>>>(
                pe, Wqkv, WqkvL, PEW, SEQ, 1536, D_MODEL);
            // QKV = xW (plain bf16) + peW (epilogue add) -> hi/lo scatter
            gemm_kernel<0, 64, 64><<<dim3(1536 / 64, NTOK / 64), 256, 0, stream>>>(
                Xraw, Wqkv, nullptr, PEW, nullptr, nullptr,
                Qhi, Qlo, Khi, Klo, Vt, NTOK, 1536, D_MODEL);
            attention_kernel<true><<<512, 256, 0, stream>>>(
                Qhi, Qlo, Khi, Klo, Vt, Ob);
        } else {
            gemm_kernel<0, 64, 64><<<dim3(1536 / 64, NTOK / 64), 256, 0, stream>>>(
                Xbf, Wqkv + (size_t)i * 1536 * 512, nullptr, nullptr, nullptr,
                nullptr, Qhi, Qlo, Khi, Klo, Vt, NTOK, 1536, D_MODEL);
            attention_kernel<false><<<512, 256, 0, stream>>>(
                Qhi, Qlo, Khi, Klo, Vt, Ob);
        }

        add_norm_kernel<<<NTOK, 256, 0, stream>>>(
            Ob, X, ln1_a + i * D_MODEL, ln1_b + i * D_MODEL, X, Xbf);

        // FFN1: M=4096, N=1024, K=512, bias+relu -> bf16 H (aliases Qhi/Qlo)
        gemm_kernel<1, 64, 64><<<dim3(D_INNER / 64, NTOK / 64), 256, 0, stream>>>(
            Xbf, W1b + (size_t)i * D_INNER * D_MODEL, b1 + (size_t)i * D_INNER,
            nullptr, nullptr, Hbf, nullptr, nullptr, nullptr, nullptr, nullptr,
            NTOK, D_INNER, D_MODEL);

        // FFN2: M=4096, N=512, K=1024, bias -> fp32 Ob
        gemm_kernel<2, 64, 64><<<dim3(D_MODEL / 64, NTOK / 64), 256, 0, stream>>>(
            Hbf, W2b + (size_t)i * D_MODEL * D_INNER, b2 + (size_t)i * D_MODEL,
            nullptr, Ob, nullptr, nullptr, nullptr, nullptr, nullptr, nullptr,
            NTOK, D_MODEL, D_INNER);

        float* dst = (i == N_LAYERS - 1) ? out : X;
        add_norm_kernel<<<NTOK, 256, 0, stream>>>(
            Ob, X, ln2_a + i * D_MODEL, ln2_b + i * D_MODEL, dst, Xbf);
    }
}

// Round 17
// 305.281 us; speedup vs baseline: 1.3457x; 1.1046x over previous
//
#include <hip/hip_runtime.h>
#include <math.h>

#define D_MODEL 512
#define SEQ     1024
#define BATCH   4
#define N_LAYERS 2
#define N_HEAD  8
#define D_HEAD  64
#define D_INNER 1024
#define NTOK    (BATCH*SEQ)   // 4096
#define LN_EPS  1e-3f

typedef float f32x4 __attribute__((ext_vector_type(4)));
typedef short bf16x8 __attribute__((ext_vector_type(8)));
typedef unsigned short ushort_t;
typedef unsigned int uint_t;
typedef unsigned long long ull_t;

// fp32 -> bf16 round-to-nearest-even
__device__ inline ushort_t f2bf(float f) {
    uint_t u = __float_as_uint(f);
    u += 0x7FFFu + ((u >> 16) & 1u);
    return (ushort_t)(u >> 16);
}
__device__ inline float bf2f(ushort_t h) {
    return __uint_as_float((uint_t)h << 16);
}

// ---------------------------------------------------------------- fused prep
// One launch replaces: add_pos, conv_qkvw x2, conv_bf16(w1), conv_bf16(w2).
#define PREP_E0 (NTOK * D_MODEL)                  // 2,097,152
#define PREP_E1 (1536 * 512)                      // 786,432
#define PREP_EW (N_LAYERS * D_INNER * D_MODEL)    // 1,048,576
#define PREP_TOTAL (PREP_E0 + 2 * PREP_E1 + 2 * PREP_EW)

__global__ void prep_kernel(const float* __restrict__ x,
                            const float* __restrict__ pe,
                            const float* __restrict__ w_qs,
                            const float* __restrict__ w_ks,
                            const float* __restrict__ w_vs,
                            const float* __restrict__ w1,
                            const float* __restrict__ w2,
                            float* __restrict__ X,
                            ushort_t* __restrict__ Xraw,
                            ushort_t* __restrict__ Wqkv,
                            ushort_t* __restrict__ WqkvL,
                            ushort_t* __restrict__ W1b,
                            ushort_t* __restrict__ W2b) {
    int idx = blockIdx.x * 256 + threadIdx.x;
    if (idx < PREP_E0) {
        int l = (idx / D_MODEL) % SEQ;
        int d = idx % D_MODEL;
        float xv = x[idx];
        X[idx] = xv + pe[l * D_MODEL + d];
        Xraw[idx] = f2bf(xv);
        return;
    }
    idx -= PREP_E0;
    if (idx < 2 * PREP_E1) {
        int layer = idx / PREP_E1;
        int j = idx - layer * PREP_E1;
        int n = j >> 9, k = j & 511;
        int which = n >> 9, h = (n >> 6) & 7, d = n & 63;
        size_t wofs = (size_t)layer * N_HEAD * D_MODEL * D_HEAD;
        const float* W = (which == 0) ? w_qs + wofs
                       : (which == 1) ? w_ks + wofs : w_vs + wofs;
        float v = W[((size_t)h * D_MODEL + k) * D_HEAD + d];
        ushort_t hv = f2bf(v);
        Wqkv[(size_t)layer * PREP_E1 + j] = hv;
        if (layer == 0) WqkvL[j] = f2bf(v - bf2f(hv));
        return;
    }
    idx -= 2 * PREP_E1;
    if (idx < PREP_EW) { W1b[idx] = f2bf(w1[idx]); return; }
    idx -= PREP_EW;
    W2b[idx] = f2bf(w2[idx]);
}

// ---------------------------------------------------------------- QKV scatter
__device__ inline void qkv_scatter(f32x4 a, int n, int m_base,
                                   const float* __restrict__ pew,
                                   ushort_t* Qhi, ushort_t* Qlo,
                                   ushort_t* Khi, ushort_t* Klo,
                                   ushort_t* Vt) {
    int which = n >> 9, hd = n & 511;
    int head = hd >> 6, d = hd & 63;
    int hb = head * BATCH + (m_base >> 10);
    int l  = m_base & 1023;
    if (pew) {
#pragma unroll
        for (int r = 0; r < 4; r++) a[r] += pew[(size_t)(l + r) * 1536 + n];
    }
    if (which == 2) {
        ushort4 pk = make_ushort4(f2bf(a[0]), f2bf(a[1]), f2bf(a[2]), f2bf(a[3]));
        *(ushort4*)(Vt + ((size_t)hb * D_HEAD + d) * SEQ + l) = pk;
    } else {
        ushort_t* H = (which == 0) ? Qhi : Khi;
        ushort_t* L = (which == 0) ? Qlo : Klo;
#pragma unroll
        for (int r = 0; r < 4; r++) {
            float v = a[r];
            ushort_t hv = f2bf(v);
            size_t off = ((size_t)hb * SEQ + l + r) * D_HEAD + d;
            H[off] = hv;
            L[off] = f2bf(v - bf2f(hv));
        }
    }
}

// ---------------------------------------------------------------- MFMA GEMM
// 64x64 tile (128-tiles ✗ R10), BK=128 K-staging: 16 MFMAs per barrier pair
// (halved barrier count — the R15 lever applied to the GEMM K-loop; grid
// unchanged, LDS 35 KB still fits 4 blocks/CU).
template<int MODE, int TM, int TN, int BK>
__global__ __launch_bounds__(256, 4)
void gemm_kernel(const ushort_t* __restrict__ A, const ushort_t* __restrict__ Bt,
                 const float* __restrict__ bias, const float* __restrict__ pew,
                 float* __restrict__ outF, ushort_t* __restrict__ outB,
                 ushort_t* __restrict__ Qhi, ushort_t* __restrict__ Qlo,
                 ushort_t* __restrict__ Khi, ushort_t* __restrict__ Klo,
                 ushort_t* __restrict__ Vt,
                 int M, int N, int K) {
    constexpr int WM = TM / 2, WN = TN / 2;
    constexpr int MT = WM / 16, NT = WN / 16;
    constexpr int CPR = BK / 8;            // uint4 chunks per row
    __shared__ ushort_t As[TM][BK + 8];    // +8 pad: 16B align, breaks bank alias
    __shared__ ushort_t Bs[TN][BK + 8];
    const int tid = threadIdx.x;
    const int m0 = blockIdx.y * TM, n0 = blockIdx.x * TN;
    const int w = tid >> 6, lane = tid & 63;
    const int wr = w >> 1, wc = w & 1;
    const int col = lane & 15, quad = lane >> 4;

    f32x4 acc[MT][NT] = {};

    for (int k0 = 0; k0 < K; k0 += BK) {
        __syncthreads();
#pragma unroll
        for (int p = 0; p < TM * CPR / 256; p++) {
            int idx = p * 256 + tid;
            int row = idx / CPR, ch = (idx % CPR) * 8;
            *(uint4*)(&As[row][ch]) =
                *(const uint4*)(A + (size_t)(m0 + row) * K + k0 + ch);
        }
#pragma unroll
        for (int p = 0; p < TN * CPR / 256; p++) {
            int idx = p * 256 + tid;
            int row = idx / CPR, ch = (idx % CPR) * 8;
            *(uint4*)(&Bs[row][ch]) =
                *(const uint4*)(Bt + (size_t)(n0 + row) * K + k0 + ch);
        }
        __syncthreads();
#pragma unroll
        for (int ks = 0; ks < BK; ks += 32) {
            bf16x8 af[MT], bfr[NT];
#pragma unroll
            for (int t = 0; t < MT; t++)
                af[t] = *(const bf16x8*)(&As[wr * WM + t * 16 + col][ks + quad * 8]);
#pragma unroll
            for (int t = 0; t < NT; t++)
                bfr[t] = *(const bf16x8*)(&Bs[wc * WN + t * 16 + col][ks + quad * 8]);
#pragma unroll
            for (int mt = 0; mt < MT; mt++)
#pragma unroll
                for (int nt = 0; nt < NT; nt++)
                    acc[mt][nt] = __builtin_amdgcn_mfma_f32_16x16x32_bf16(
                        af[mt], bfr[nt], acc[mt][nt], 0, 0, 0);
        }
    }

#pragma unroll
    for (int mt = 0; mt < MT; mt++) {
#pragma unroll
        for (int nt = 0; nt < NT; nt++) {
            int n = n0 + wc * WN + nt * 16 + col;
            int m_base = m0 + wr * WM + mt * 16 + quad * 4;
            if (MODE == 0) {
                qkv_scatter(acc[mt][nt], n, m_base, pew, Qhi, Qlo, Khi, Klo, Vt);
            } else {
#pragma unroll
                for (int r = 0; r < 4; r++) {
                    int m = m_base + r;
                    float v = acc[mt][nt][r];
                    if (MODE == 1) {
                        float t = fmaxf(v + bias[n], 0.f);
                        outB[(size_t)m * N + n] = f2bf(t);
                    } else {
                        outF[(size_t)m * N + n] = v + bias[n];
                    }
                }
            }
        }
    }
}

// ---------------------------------------------------------------- hi/lo GEMM
// Used for peW = pos_enc @ Wqkv (M=SEQ=1024). fp32 out [M][N]. BK=64 (4
// staged arrays; BK=128 would hit 70 KB LDS and halve residency).
__global__ __launch_bounds__(256, 4)
void gemm_hilo_kernel(const float* __restrict__ A,
                      const ushort_t* __restrict__ Bh,
                      const ushort_t* __restrict__ Bl,
                      float* __restrict__ outF, int M, int N, int K) {
    __shared__ ushort_t Ash[64][72];
    __shared__ ushort_t Asl[64][72];
    __shared__ ushort_t Bsh[64][72];
    __shared__ ushort_t Bsl[64][72];
    const int tid = threadIdx.x;
    const int m0 = blockIdx.y * 64, n0 = blockIdx.x * 64;
    const int w = tid >> 6, lane = tid & 63;
    const int wm = (w >> 1) * 32, wn = (w & 1) * 32;
    const int col = lane & 15, quad = lane >> 4;

    f32x4 acc[2][2] = {};

    for (int k0 = 0; k0 < K; k0 += 64) {
        __syncthreads();
#pragma unroll
        for (int p = 0; p < 4; p++) {
            int idx = p * 256 + tid;
            int row = idx >> 4, c4 = (idx & 15) * 4;
            float4 v = *(const float4*)(A + (size_t)(m0 + row) * K + k0 + c4);
            ushort_t h0 = f2bf(v.x), h1 = f2bf(v.y), h2 = f2bf(v.z), h3 = f2bf(v.w);
            *(ushort4*)(&Ash[row][c4]) = make_ushort4(h0, h1, h2, h3);
            *(ushort4*)(&Asl[row][c4]) = make_ushort4(
                f2bf(v.x - bf2f(h0)), f2bf(v.y - bf2f(h1)),
                f2bf(v.z - bf2f(h2)), f2bf(v.w - bf2f(h3)));
        }
#pragma unroll
        for (int p = 0; p < 2; p++) {
            int idx = p * 256 + tid;
            int row = idx >> 3, ch = (idx & 7) * 8;
            *(uint4*)(&Bsh[row][ch]) =
                *(const uint4*)(Bh + (size_t)(n0 + row) * K + k0 + ch);
            *(uint4*)(&Bsl[row][ch]) =
                *(const uint4*)(Bl + (size_t)(n0 + row) * K + k0 + ch);
        }
        __syncthreads();
#pragma unroll
        for (int ks = 0; ks < 64; ks += 32) {
            bf16x8 ah[2], al[2], bh[2], bl[2];
#pragma unroll
            for (int t = 0; t < 2; t++) {
                ah[t] = *(const bf16x8*)(&Ash[wm + t * 16 + col][ks + quad * 8]);
                al[t] = *(const bf16x8*)(&Asl[wm + t * 16 + col][ks + quad * 8]);
                bh[t] = *(const bf16x8*)(&Bsh[wn + t * 16 + col][ks + quad * 8]);
                bl[t] = *(const bf16x8*)(&Bsl[wn + t * 16 + col][ks + quad * 8]);
            }
#pragma unroll
            for (int mt = 0; mt < 2; mt++)
#pragma unroll
                for (int nt = 0; nt < 2; nt++) {
                    acc[mt][nt] = __builtin_amdgcn_mfma_f32_16x16x32_bf16(
                        ah[mt], bh[nt], acc[mt][nt], 0, 0, 0);
                    acc[mt][nt] = __builtin_amdgcn_mfma_f32_16x16x32_bf16(
                        ah[mt], bl[nt], acc[mt][nt], 0, 0, 0);
                    acc[mt][nt] = __builtin_amdgcn_mfma_f32_16x16x32_bf16(
                        al[mt], bh[nt], acc[mt][nt], 0, 0, 0);
                }
        }
    }

#pragma unroll
    for (int mt = 0; mt < 2; mt++)
#pragma unroll
        for (int nt = 0; nt < 2; nt++) {
            int n = n0 + wn + nt * 16 + col;
#pragma unroll
            for (int r = 0; r < 4; r++) {
                int m = m0 + wm + mt * 16 + quad * 4 + r;
                outF[(size_t)m * N + n] = acc[mt][nt][r];
            }
        }
}

// ---------------------------------------------------------------- attention
// MFMA flash attention — single-LDS-buffer, TK=128 (two 64-key subtiles per
// barrier pair — R15 win). TBAA fence before the P round-trip. HILO: layer 1.
template<bool HILO>
__global__ __launch_bounds__(256, 2)
void attention_kernel(const ushort_t* __restrict__ Qhi,
                      const ushort_t* __restrict__ Qlo,
                      const ushort_t* __restrict__ Khi,
                      const ushort_t* __restrict__ Klo,
                      const ushort_t* __restrict__ Vt,
                      float* __restrict__ O) {
    const int bid = blockIdx.x;          // 512
    const int j   = bid >> 3;
    const int hb  = (bid & 7) * 4 + (j >> 4);
    const int qt  = j & 15;
    const int h = hb >> 2, b = hb & 3;
    const int tid = threadIdx.x;
    const int w = tid >> 6, lane = tid & 63;
    const int col = lane & 15, quad = lane >> 4;
    const size_t kbase = (size_t)hb * SEQ * D_HEAD;
    const size_t vbase = (size_t)hb * D_HEAD * SEQ;

    __shared__ ushort_t Kh[128][72];             // 18 KB (keys x dims)
    __shared__ ushort_t Kl[HILO ? 128 : 1][72];  // 18 KB when HILO
    __shared__ ushort_t Vs[64][136];             // 17 KB (dims x 128 keys)
    __shared__ ushort_t Pl[4][16][68];           // per-wave P, 8.5 KB

    bf16x8 qh[2], ql[2];
    {
        const ushort_t* qp = Qhi + kbase + (size_t)(qt * 64 + w * 16 + col) * D_HEAD;
        qh[0] = *(const bf16x8*)(qp + quad * 8);
        qh[1] = *(const bf16x8*)(qp + 32 + quad * 8);
        if (HILO) {
            const ushort_t* lp = Qlo + kbase + (size_t)(qt * 64 + w * 16 + col) * D_HEAD;
            ql[0] = *(const bf16x8*)(lp + quad * 8);
            ql[1] = *(const bf16x8*)(lp + 32 + quad * 8);
        }
    }

    f32x4 acco[4] = {};
    float mrun[4], lrun[4];
#pragma unroll
    for (int r = 0; r < 4; r++) { mrun[r] = -1e30f; lrun[r] = 0.f; }
    const float inv_temper = 0.04419417382415922f;  // 1/sqrt(512)

    for (int t0 = 0; t0 < SEQ; t0 += 128) {
        __syncthreads();
#pragma unroll
        for (int p = 0; p < 4; p++) {
            int idx = p * 256 + tid;
            int row = idx >> 3, ch = (idx & 7) * 8;
            *(uint4*)(&Kh[row][ch]) =
                *(const uint4*)(Khi + kbase + (size_t)(t0 + row) * D_HEAD + ch);
            if (HILO)
                *(uint4*)(&Kl[row][ch]) =
                    *(const uint4*)(Klo + kbase + (size_t)(t0 + row) * D_HEAD + ch);
        }
#pragma unroll
        for (int p = 0; p < 4; p++) {
            int idx = p * 256 + tid;
            int row = idx >> 4, ch = (idx & 15) * 8;
            *(uint4*)(&Vs[row][ch]) =
                *(const uint4*)(Vt + vbase + (size_t)row * SEQ + t0 + ch);
        }
        __syncthreads();

#pragma unroll
        for (int st = 0; st < 2; st++) {
            const int ko = st * 64;

            float sc[4][4];
#pragma unroll
            for (int nt = 0; nt < 4; nt++) {
                bf16x8 bh0 = *(const bf16x8*)(&Kh[ko + nt * 16 + col][quad * 8]);
                bf16x8 bh1 = *(const bf16x8*)(&Kh[ko + nt * 16 + col][32 + quad * 8]);
                f32x4 s = {};
                s = __builtin_amdgcn_mfma_f32_16x16x32_bf16(qh[0], bh0, s, 0, 0, 0);
                s = __builtin_amdgcn_mfma_f32_16x16x32_bf16(qh[1], bh1, s, 0, 0, 0);
                if (HILO) {
                    bf16x8 bl0 = *(const bf16x8*)(&Kl[ko + nt * 16 + col][quad * 8]);
                    bf16x8 bl1 = *(const bf16x8*)(&Kl[ko + nt * 16 + col][32 + quad * 8]);
                    s = __builtin_amdgcn_mfma_f32_16x16x32_bf16(qh[0], bl0, s, 0, 0, 0);
                    s = __builtin_amdgcn_mfma_f32_16x16x32_bf16(qh[1], bl1, s, 0, 0, 0);
                    s = __builtin_amdgcn_mfma_f32_16x16x32_bf16(ql[0], bh0, s, 0, 0, 0);
                    s = __builtin_amdgcn_mfma_f32_16x16x32_bf16(ql[1], bh1, s, 0, 0, 0);
                }
#pragma unroll
                for (int r = 0; r < 4; r++) sc[nt][r] = s[r] * inv_temper;
            }

            float tmax[4];
#pragma unroll
            for (int r = 0; r < 4; r++)
                tmax[r] = fmaxf(fmaxf(sc[0][r], sc[1][r]), fmaxf(sc[2][r], sc[3][r]));
#pragma unroll
            for (int mask = 1; mask < 16; mask <<= 1)
#pragma unroll
                for (int r = 0; r < 4; r++)
                    tmax[r] = fmaxf(tmax[r], __shfl_xor(tmax[r], mask, 64));

            float alpha[4], tsum[4];
#pragma unroll
            for (int r = 0; r < 4; r++) {
                float mn = fmaxf(mrun[r], tmax[r]);
                alpha[r] = __expf(mrun[r] - mn);
                mrun[r] = mn;
                tsum[r] = 0.f;
            }
#pragma unroll
            for (int nt = 0; nt < 4; nt++)
#pragma unroll
                for (int r = 0; r < 4; r++) {
                    float pv = __expf(sc[nt][r] - mrun[r]);
                    tsum[r] += pv;
                    Pl[w][quad * 4 + r][nt * 16 + col] = f2bf(pv);
                }
#pragma unroll
            for (int mask = 1; mask < 16; mask <<= 1)
#pragma unroll
                for (int r = 0; r < 4; r++)
                    tsum[r] += __shfl_xor(tsum[r], mask, 64);
#pragma unroll
            for (int r = 0; r < 4; r++)
                lrun[r] = lrun[r] * alpha[r] + tsum[r];
#pragma unroll
            for (int nt = 0; nt < 4; nt++)
#pragma unroll
                for (int r = 0; r < 4; r++)
                    acco[nt][r] *= alpha[r];

            __threadfence_block();

            union { ulong2 u; bf16x8 v; } a0, a1;
            a0.u.x = *(const ull_t*)(&Pl[w][col][quad * 8]);
            a0.u.y = *(const ull_t*)(&Pl[w][col][quad * 8 + 4]);
            a1.u.x = *(const ull_t*)(&Pl[w][col][32 + quad * 8]);
            a1.u.y = *(const ull_t*)(&Pl[w][col][32 + quad * 8 + 4]);
#pragma unroll
            for (int nt = 0; nt < 4; nt++) {
                bf16x8 bv0 = *(const bf16x8*)(&Vs[nt * 16 + col][ko + quad * 8]);
                bf16x8 bv1 = *(const bf16x8*)(&Vs[nt * 16 + col][ko + 32 + quad * 8]);
                acco[nt] = __builtin_amdgcn_mfma_f32_16x16x32_bf16(a0.v, bv0, acco[nt], 0, 0, 0);
                acco[nt] = __builtin_amdgcn_mfma_f32_16x16x32_bf16(a1.v, bv1, acco[nt], 0, 0, 0);
            }
        }
    }

#pragma unroll
    for (int nt = 0; nt < 4; nt++) {
#pragma unroll
        for (int r = 0; r < 4; r++) {
            int row = qt * 64 + w * 16 + quad * 4 + r;
            O[((size_t)b * SEQ + row) * D_MODEL + h * D_HEAD + nt * 16 + col]
                = acco[nt][r] / lrun[r];
        }
    }
}

// ---------------------------------------------------------------- add + LN
__device__ inline float block_sum_256(float v, float* tmp) {
#pragma unroll
    for (int off = 32; off > 0; off >>= 1) v += __shfl_down(v, off, 64);
    if ((threadIdx.x & 63) == 0) tmp[threadIdx.x >> 6] = v;
    __syncthreads();
    return tmp[0] + tmp[1] + tmp[2] + tmp[3];
}

// Writes fp32 Out AND bf16 OutBf. Safe for Out==R (in-place).
__global__ void add_norm_kernel(const float* __restrict__ A,
                                const float* __restrict__ R,
                                const float* __restrict__ ga,
                                const float* __restrict__ gb,
                                float* __restrict__ Out,
                                ushort_t* __restrict__ OutBf) {
    int tok = blockIdx.x, tid = threadIdx.x;
    __shared__ float t1[4], t2[4];
    size_t base = (size_t)tok * D_MODEL;
    float z0 = A[base + tid]       + R[base + tid];
    float z1 = A[base + tid + 256] + R[base + tid + 256];
    float s = block_sum_256(z0 + z1, t1);
    float mu = s * (1.f / (float)D_MODEL);
    float d0 = z0 - mu, d1 = z1 - mu;
    float ss = block_sum_256(d0 * d0 + d1 * d1, t2);
    float sigma = sqrtf(ss * (1.f / (float)(D_MODEL - 1)));
    float inv = 1.f / (sigma + LN_EPS);
    float r0 = d0 * inv * ga[tid]       + gb[tid];
    float r1 = d1 * inv * ga[tid + 256] + gb[tid + 256];
    Out[base + tid]         = r0;
    Out[base + tid + 256]   = r1;
    OutBf[base + tid]       = f2bf(r0);
    OutBf[base + tid + 256] = f2bf(r1);
}

// ---------------------------------------------------------------- launch
extern "C" void kernel_launch(void* const* d_in, const int* in_sizes, int n_in,
                              void* d_out, int out_size, void* d_ws, size_t ws_size,
                              hipStream_t stream) {
    const float* x     = (const float*)d_in[0];
    const float* pe    = (const float*)d_in[1];
    const float* w_qs  = (const float*)d_in[2];
    const float* w_ks  = (const float*)d_in[3];
    const float* w_vs  = (const float*)d_in[4];
    const float* ln1_a = (const float*)d_in[5];
    const float* ln1_b = (const float*)d_in[6];
    const float* w1    = (const float*)d_in[7];
    const float* b1    = (const float*)d_in[8];
    const float* w2    = (const float*)d_in[9];
    const float* b2    = (const float*)d_in[10];
    const float* ln2_a = (const float*)d_in[11];
    const float* ln2_b = (const float*)d_in[12];
    float* out = (float*)d_out;

    const size_t NXD = (size_t)NTOK * D_MODEL;       // 2M elements
    char* p = (char*)d_ws;
    float*    X    = (float*)p;     p += NXD * 4;                 // 8 MB
    float*    Ob   = (float*)p;     p += NXD * 4;                 // 8 MB
    ushort_t* Xbf  = (ushort_t*)p;  p += NXD * 2;                 // 4 MB
    ushort_t* Xraw = (ushort_t*)p;  p += NXD * 2;                 // 4 MB  bf16(x)
    ushort_t* Qhi  = (ushort_t*)p;  p += NXD * 2;                 // 4 MB
    ushort_t* Qlo  = (ushort_t*)p;  p += NXD * 2;                 // 4 MB
    ushort_t* Khi  = (ushort_t*)p;  p += NXD * 2;                 // 4 MB
    ushort_t* Klo  = (ushort_t*)p;  p += NXD * 2;                 // 4 MB
    ushort_t* Vt   = (ushort_t*)p;  p += NXD * 2;                 // 4 MB
    ushort_t* Wqkv = (ushort_t*)p;  p += (size_t)N_LAYERS * 1536 * 512 * 2;  // 3 MB (hi)
    ushort_t* WqkvL= (ushort_t*)p;  p += (size_t)1536 * 512 * 2;  // 1.5 MB (lo, layer 0)
    ushort_t* W1b  = (ushort_t*)p;  p += (size_t)N_LAYERS * D_INNER * D_MODEL * 2;  // 2 MB
    ushort_t* W2b  = (ushort_t*)p;  /* 2 MB */
    // Aliases (stream-ordered safe): H = Qhi/Qlo (dead after attention);
    // PEW = Ob (produced+consumed before attention writes Ob in layer 1).
    ushort_t* Hbf  = Qhi;
    float*    PEW  = Ob;

    prep_kernel<<<(PREP_TOTAL + 255) / 256, 256, 0, stream>>>(
        x, pe, w_qs, w_ks, w_vs, w1, w2, X, Xraw, Wqkv, WqkvL, W1b, W2b);

    for (int i = 0; i < N_LAYERS; i++) {
        if (i == 0) {
            gemm_hilo_kernel<<<dim3(1536 / 64, SEQ / 64), 256, 0, stream>>>(
                pe, Wqkv, WqkvL, PEW, SEQ, 1536, D_MODEL);
            gemm_kernel<0, 64, 64, 128><<<dim3(1536 / 64, NTOK / 64), 256, 0, stream>>>(
                Xraw, Wqkv, nullptr, PEW, nullptr, nullptr,
                Qhi, Qlo, Khi, Klo, Vt, NTOK, 1536, D_MODEL);
            attention_kernel<true><<<512, 256, 0, stream>>>(
                Qhi, Qlo, Khi, Klo, Vt, Ob);
        } else {
            gemm_kernel<0, 64, 64, 128><<<dim3(1536 / 64, NTOK / 64), 256, 0, stream>>>(
                Xbf, Wqkv + (size_t)i * 1536 * 512, nullptr, nullptr, nullptr,
                nullptr, Qhi, Qlo, Khi, Klo, Vt, NTOK, 1536, D_MODEL);
            attention_kernel<false><<<512, 256, 0, stream>>>(
                Qhi, Qlo, Khi, Klo, Vt, Ob);
        }

        add_norm_kernel<<<NTOK, 256, 0, stream>>>(
            Ob, X, ln1_a + i * D_MODEL, ln1_b + i * D_MODEL, X, Xbf);

        // FFN1: M=4096, N=1024, K=512, bias+relu -> bf16 H (aliases Qhi/Qlo)
        gemm_kernel<1, 64, 64, 128><<<dim3(D_INNER / 64, NTOK / 64), 256, 0, stream>>>(
            Xbf, W1b + (size_t)i * D_INNER * D_MODEL, b1 + (size_t)i * D_INNER,
            nullptr, nullptr, Hbf, nullptr, nullptr, nullptr, nullptr, nullptr,
            NTOK, D_INNER, D_MODEL);

        // FFN2: M=4096, N=512, K=1024, bias -> fp32 Ob
        gemm_kernel<2, 64, 64, 128><<<dim3(D_MODEL / 64, NTOK / 64), 256, 0, stream>>>(
            Hbf, W2b + (size_t)i * D_MODEL * D_INNER, b2 + (size_t)i * D_MODEL,
            nullptr, Ob, nullptr, nullptr, nullptr, nullptr, nullptr, nullptr,
            NTOK, D_MODEL, D_INNER);

        float* dst = (i == N_LAYERS - 1) ? out : X;
        add_norm_kernel<<<NTOK, 256, 0, stream>>>(
            Ob, X, ln2_a + i * D_MODEL, ln2_b + i * D_MODEL, dst, Xbf);
    }
}